// Round 1
// baseline (134788.757 us; speedup 1.0000x reference)
//
#include <hip/hip_runtime.h>

namespace {
constexpr int kB  = 32;
constexpr int kT  = 1024;
constexpr int kD  = 512;
constexpr int kH  = 1024;
constexpr int kLV = 128;
constexpr int kNG = 4 * kH + 2 * kLV;   // 4352 gate columns (4096 lstm + 256 lvl)
constexpr int kNBLK = 256;
constexpr int kNTHR = 256;
constexpr int kCPB  = kNG / kNBLK;      // 17 columns per block
constexpr int kBK   = 256;              // K-chunk staged in LDS
}

__device__ __forceinline__ unsigned ld_flag(unsigned* p) {
  return __hip_atomic_load(p, __ATOMIC_RELAXED, __HIP_MEMORY_SCOPE_AGENT);
}
__device__ __forceinline__ void st_flag(unsigned* p, unsigned v) {
  __hip_atomic_store(p, v, __ATOMIC_RELAXED, __HIP_MEMORY_SCOPE_AGENT);
}

__global__ __launch_bounds__(kNTHR) void onlstm_kernel(
    const float* __restrict__ x,
    const float* __restrict__ Wl0, const float* __restrict__ bl0,
    const float* __restrict__ Wv0, const float* __restrict__ bv0,
    const float* __restrict__ Wl1, const float* __restrict__ bl1,
    const float* __restrict__ Wv1, const float* __restrict__ bv1,
    float* __restrict__ out,   // [32][1024][1024]; also holds layer-0 output
    float* __restrict__ ws)
{
  const unsigned tid = threadIdx.x;
  const unsigned bid = blockIdx.x;

  // ---- workspace layout (floats) ----
  unsigned* flags = (unsigned*)ws;            // [256] per-block arrival flags
  unsigned* genp  = (unsigned*)ws + 1024;     // generation (release) word
  float* h     = ws + 2048;                   // [32][1024]
  float* c     = h + kB * kH;                 // [32][1024]
  float* gates = c + kB * kH;                 // [32][4352]

  __shared__ float comb_lds[kB * (kBK + 4)];  // 32 x 260 floats (33280 B)
  __shared__ float red[8 * kB * kCPB];        // [s][b][c] partials (17408 B)
  __shared__ float ih_sh[kLV], fh_sh[kLV];
  __shared__ float smx[8];

  unsigned seq = 0;

  auto gridbar = [&]() {
    ++seq;
    __syncthreads();                          // block stores drained to L2
    if (tid == 0)
      __builtin_amdgcn_fence(__ATOMIC_RELEASE, "agent");  // L2 -> coherent point
    if (bid == 0) {
      if (tid > 0) {
        while (ld_flag(&flags[tid]) != seq) __builtin_amdgcn_s_sleep(1);
      }
      __syncthreads();                        // all flags observed
      if (tid == 0) st_flag(genp, seq);
    } else {
      if (tid == 0) {
        st_flag(&flags[bid], seq);
        while (ld_flag(genp) != seq) __builtin_amdgcn_s_sleep(1);
      }
      __syncthreads();
    }
    __builtin_amdgcn_fence(__ATOMIC_ACQUIRE, "agent");    // invalidate stale L1/L2
  };

  const unsigned s_  = tid >> 5;   // K-slice 0..7
  const unsigned bb  = tid & 31;   // batch row
  const int j0 = bid * kCPB;

  for (int layer = 0; layer < 2; ++layer) {
    const int IN = layer ? kH : kD;
    const int K  = IN + kH;
    const int nchunk = K / kBK;                 // 6 or 8
    const float* xin = layer ? out : x;         // layer-1 input = layer-0 output
    const float* Wl  = layer ? Wl1 : Wl0;
    const float* Wv  = layer ? Wv1 : Wv0;
    const float* bl  = layer ? bl1 : bl0;
    const float* bv  = layer ? bv1 : bv0;

    // zero h, c
    {
      int idx = bid * kNTHR + tid;
      if (idx < kB * kH) { h[idx] = 0.f; c[idx] = 0.f; }
    }
    gridbar();

    // per-column weight row pointers (block-uniform -> scalar regs)
    const float* wrow[kCPB];
#pragma unroll
    for (int cc2 = 0; cc2 < kCPB; ++cc2) {
      int j = j0 + cc2;
      wrow[cc2] = (j < 4 * kH) ? (Wl + (size_t)j * K)
                               : (Wv + (size_t)(j - 4 * kH) * K);
    }

    for (int t = 0; t < kT; ++t) {
      // ================= Phase A: gates = [x_t, h] @ W^T + b =================
      float acc[kCPB];
#pragma unroll
      for (int cc2 = 0; cc2 < kCPB; ++cc2) acc[cc2] = 0.f;

      for (int kc = 0; kc < nchunk; ++kc) {
        const int kbase = kc * kBK;
        // stage comb chunk [32][256] into LDS (coalesced float4)
#pragma unroll
        for (int it = 0; it < 8; ++it) {
          int fq = it * kNTHR + tid;            // 0..2047 quads
          int br = fq >> 6;                     // 0..31
          int q  = fq & 63;
          int k  = kbase + q * 4;
          const float* src = (k < IN)
              ? (xin + ((size_t)br * kT + t) * IN + k)
              : (h + br * kH + (k - IN));
          float4 v = *(const float4*)src;
          *(float4*)&comb_lds[br * (kBK + 4) + q * 4] = v;
        }
        __syncthreads();
        // each thread: slice s_, row bb, all 17 columns
        const float* cb = &comb_lds[bb * (kBK + 4) + s_ * 32];
#pragma unroll
        for (int q8 = 0; q8 < 8; ++q8) {
          float4 cv = *(const float4*)&cb[q8 * 4];
          const int ko = kbase + (int)s_ * 32 + q8 * 4;
#pragma unroll
          for (int cc2 = 0; cc2 < kCPB; ++cc2) {
            float4 wv = *(const float4*)&wrow[cc2][ko];
            acc[cc2] = fmaf(cv.x, wv.x, acc[cc2]);
            acc[cc2] = fmaf(cv.y, wv.y, acc[cc2]);
            acc[cc2] = fmaf(cv.z, wv.z, acc[cc2]);
            acc[cc2] = fmaf(cv.w, wv.w, acc[cc2]);
          }
        }
        __syncthreads();
      }
      // reduce the 8 K-slices
#pragma unroll
      for (int cc2 = 0; cc2 < kCPB; ++cc2)
        red[(s_ * kB + bb) * kCPB + cc2] = acc[cc2];
      __syncthreads();
      for (int o = tid; o < kB * kCPB; o += kNTHR) {
        int cc2 = o >> 5;
        int br  = o & 31;
        float sum = 0.f;
#pragma unroll
        for (int s2 = 0; s2 < 8; ++s2) sum += red[(s2 * kB + br) * kCPB + cc2];
        int j = j0 + cc2;
        float bias = (j < 4 * kH) ? bl[j] : bv[j - 4 * kH];
        gates[(size_t)br * kNG + j] = sum + bias;
      }
      gridbar();

      // ================= Phase B: masters + cell update =================
      {
        const unsigned pb    = bid >> 3;   // batch row 0..31
        const unsigned chunk = bid & 7;    // 128-col chunk
        const float* gr = gates + (size_t)pb * kNG;
        const unsigned lane = tid & 63, wv2 = tid >> 6;
        const bool act = tid < 128;

        float ai = 0.f, af = 0.f;
        if (act) { ai = gr[4096 + tid]; af = gr[4096 + kLV + tid]; }
        float mi = ai, mf = af;
        if (act) {
#pragma unroll
          for (int d2 = 32; d2 > 0; d2 >>= 1) {
            mi = fmaxf(mi, __shfl_xor(mi, d2));
            mf = fmaxf(mf, __shfl_xor(mf, d2));
          }
          if (lane == 0) { smx[wv2] = mi; smx[2 + wv2] = mf; }
        }
        __syncthreads();
        mi = fmaxf(smx[0], smx[1]);
        mf = fmaxf(smx[2], smx[3]);
        float ei = 0.f, ef = 0.f, Pi = 0.f, Pf = 0.f;
        if (act) {
          ei = __expf(ai - mi); ef = __expf(af - mf);
          Pi = ei; Pf = ef;
#pragma unroll
          for (int d2 = 1; d2 < 64; d2 <<= 1) {
            float ni = __shfl_up(Pi, d2);
            float nf = __shfl_up(Pf, d2);
            if ((int)lane >= d2) { Pi += ni; Pf += nf; }
          }
          if (lane == 63) { smx[4 + wv2] = Pi; smx[6 + wv2] = Pf; }
        }
        __syncthreads();
        float Si = smx[4] + smx[5], Sf = smx[6] + smx[7];
        if (act) {
          if (wv2 == 1) { Pi += smx[4]; Pf += smx[6]; }
          ih_sh[tid] = Pf / Sf;                  // cumsum(softmax(cc_f_h))
          fh_sh[tid] = (Si - Pi + ei) / Si;      // suffix-sum(softmax(cc_i_h))
        }
        __syncthreads();
        if (act) {
          int j = chunk * 128 + tid;
          float vi = gr[j];
          float vf = gr[kH + j];
          float vo = gr[2 * kH + j];
          float vg = gr[3 * kH + j];
          float i_ = 1.f / (1.f + __expf(-vi));
          float f_ = 1.f / (1.f + __expf(-vf));
          float o_ = 1.f / (1.f + __expf(-vo));
          float g_ = tanhf(vg);
          int l2 = j >> 3;                       // repeat(NREP=8)
          float ih = ih_sh[l2], fh = fh_sh[l2];
          float w  = ih * fh;
          size_t ci = (size_t)pb * kH + j;
          float cold = c[ci];
          float cn = w * (f_ * cold + i_ * g_) + (fh - w) * cold + (ih - w) * g_;
          float hn = o_ * tanhf(cn);
          c[ci] = cn;
          h[ci] = hn;
          out[((size_t)pb * kT + t) * kH + j] = hn;
        }
      }
      gridbar();
    }
  }
}

extern "C" void kernel_launch(void* const* d_in, const int* in_sizes, int n_in,
                              void* d_out, int out_size, void* d_ws, size_t ws_size,
                              hipStream_t stream) {
  const float* x   = (const float*)d_in[0];
  const float* Wl0 = (const float*)d_in[1];
  const float* bl0 = (const float*)d_in[2];
  const float* Wv0 = (const float*)d_in[3];
  const float* bv0 = (const float*)d_in[4];
  const float* Wl1 = (const float*)d_in[5];
  const float* bl1 = (const float*)d_in[6];
  const float* Wv1 = (const float*)d_in[7];
  const float* bv1 = (const float*)d_in[8];
  (void)in_sizes; (void)n_in; (void)out_size; (void)ws_size;

  onlstm_kernel<<<dim3(kNBLK), dim3(kNTHR), 0, stream>>>(
      x, Wl0, bl0, Wv0, bv0, Wl1, bl1, Wv1, bv1,
      (float*)d_out, (float*)d_ws);
}

// Round 2
// 105751.270 us; speedup vs baseline: 1.2746x; 1.2746x over previous
//
#include <hip/hip_runtime.h>

namespace {
constexpr int kB  = 32;
constexpr int kT  = 1024;
constexpr int kD  = 512;
constexpr int kH  = 1024;
constexpr int kLV = 128;
constexpr int kNG = 4 * kH + 2 * kLV;   // 4352
constexpr int kNBLK = 256;
constexpr int kNTHR = 512;
constexpr int kCPB  = kNG / kNBLK;      // 17 cols per block
constexpr int kBK   = 256;              // K-chunk staged in LDS
constexpr int kSTR  = kBK + 4;          // comb row stride (4-way bank conflict only)
}

typedef float vfloat4 __attribute__((ext_vector_type(4)));

__device__ __forceinline__ unsigned ld_flag(const unsigned* p) {
  return __hip_atomic_load(p, __ATOMIC_RELAXED, __HIP_MEMORY_SCOPE_AGENT);
}
__device__ __forceinline__ void st_flag(unsigned* p, unsigned v) {
  __hip_atomic_store(p, v, __ATOMIC_RELAXED, __HIP_MEMORY_SCOPE_AGENT);
}
// coherent (L2-bypassing) scalar load — reads at L3/coherent point
__device__ __forceinline__ float ld_coh(const float* p) {
  return __hip_atomic_load(p, __ATOMIC_RELAXED, __HIP_MEMORY_SCOPE_AGENT);
}

__global__ __launch_bounds__(kNTHR, 2) void onlstm_kernel(
    const float* __restrict__ x,
    const float* __restrict__ Wl0, const float* __restrict__ bl0,
    const float* __restrict__ Wv0, const float* __restrict__ bv0,
    const float* __restrict__ Wl1, const float* __restrict__ bl1,
    const float* __restrict__ Wv1, const float* __restrict__ bv1,
    float* __restrict__ out,   // [32][1024][1024]; also holds layer-0 output
    float* __restrict__ ws)
{
  const int tid = threadIdx.x;
  const int bid = blockIdx.x;

  // ---- workspace layout ----
  unsigned* flags = (unsigned*)ws;            // [256] flags, 64B-strided
  unsigned* genp  = (unsigned*)ws + 4160;     // generation word (own line)
  float* h     = ws + 8192;                   // [32][1024]
  float* gates = h + kB * kH;                 // [32][4352]

  // comb tile [32][kSTR] (8320 fl) overlaid with red [16][32][17] (8704 fl)
  __shared__ float sbuf[16 * kB * kCPB];
  __shared__ float ih_sh[kLV], fh_sh[kLV];
  __shared__ float smx[8];

  unsigned seq = 0;

  auto gridbar = [&]() {
    ++seq;
    __syncthreads();                          // all waves' stores vmcnt-drained
    if (tid == 0)
      __builtin_amdgcn_fence(__ATOMIC_RELEASE, "agent");  // wbl2 -> L3
    if (bid == 0) {
      if (tid >= 1 && tid < kNBLK) {
        while (ld_flag(&flags[tid * 16]) != seq) __builtin_amdgcn_s_sleep(1);
      }
      __syncthreads();
      if (tid == 0) st_flag(genp, seq);
    } else {
      if (tid == 0) {
        st_flag(&flags[bid * 16], seq);
        while (ld_flag(genp) != seq) __builtin_amdgcn_s_sleep(1);
      }
      __syncthreads();
    }
    asm volatile("" ::: "memory");
  };

  const int s_ = tid >> 5;        // K-slice 0..15
  const int bb = tid & 31;        // batch row
  const int j0 = bid * kCPB;

  for (int layer = 0; layer < 2; ++layer) {
    const int IN = layer ? kH : kD;
    const int K  = IN + kH;
    const int nchunk = K / kBK;                 // 6 or 8
    const float* xin = layer ? out : x;
    const float* Wl  = layer ? Wl1 : Wl0;
    const float* Wv  = layer ? Wv1 : Wv0;
    const float* bl  = layer ? bl1 : bl0;
    const float* bv  = layer ? bv1 : bv0;

    // zero h (global); c lives in registers of phase-B threads
    for (int idx = bid * kNTHR + tid; idx < kB * kH; idx += kNBLK * kNTHR)
      h[idx] = 0.f;
    float creg = 0.f;
    gridbar();

    const float* wrow[kCPB];
#pragma unroll
    for (int cc = 0; cc < kCPB; ++cc) {
      int j = j0 + cc;
      wrow[cc] = (j < 4 * kH) ? (Wl + (size_t)j * K)
                              : (Wv + (size_t)(j - 4 * kH) * K);
    }

    for (int t = 0; t < kT; ++t) {
      // ========== Phase A: gates = [x_t, h] @ W^T + b ==========
      float acc[kCPB];
#pragma unroll
      for (int cc = 0; cc < kCPB; ++cc) acc[cc] = 0.f;

      for (int kc = 0; kc < nchunk; ++kc) {
        const int kbase = kc * kBK;
        // ---- stage comb chunk [32][256] into LDS ----
        vfloat4 v[4];
#pragma unroll
        for (int it = 0; it < 4; ++it) {
          int fq = it * kNTHR + tid;            // 0..2047 quads
          int br = fq >> 6;
          int q  = fq & 63;
          int k  = kbase + q * 4;
          if (k < IN) {
            const float* src = xin + ((size_t)br * kT + t) * IN + k;
            if (layer == 0) {
              v[it] = *(const vfloat4*)src;     // x: immutable, plain (L2-hot)
            } else {                             // out: mutable -> coherent 16B
              asm volatile("global_load_dwordx4 %0, %1, off sc0 sc1"
                           : "=v"(v[it]) : "v"(src));
            }
          } else {
            const float* src = h + br * kH + (k - IN);
            asm volatile("global_load_dwordx4 %0, %1, off sc0 sc1"
                         : "=v"(v[it]) : "v"(src));
          }
        }
        asm volatile("s_waitcnt vmcnt(0)" ::: "memory");
        __builtin_amdgcn_sched_barrier(0);
#pragma unroll
        for (int it = 0; it < 4; ++it) {
          int fq = it * kNTHR + tid;
          int br = fq >> 6;
          int q  = fq & 63;
          *(vfloat4*)&sbuf[br * kSTR + q * 4] = v[it];
        }
        __syncthreads();

        // ---- FMA: slice s_ (16 floats), 17 cols, weights from L2 ----
        const float* cb = &sbuf[bb * kSTR + s_ * 16];
#pragma unroll
        for (int q8 = 0; q8 < 4; ++q8) {
          vfloat4 cv = *(const vfloat4*)&cb[q8 * 4];
          const int ko = kbase + s_ * 16 + q8 * 4;
#pragma unroll
          for (int cc = 0; cc < kCPB; ++cc) {
            vfloat4 wv = *(const vfloat4*)(wrow[cc] + ko);
            acc[cc] = fmaf(cv.x, wv.x, acc[cc]);
            acc[cc] = fmaf(cv.y, wv.y, acc[cc]);
            acc[cc] = fmaf(cv.z, wv.z, acc[cc]);
            acc[cc] = fmaf(cv.w, wv.w, acc[cc]);
          }
        }
        __syncthreads();
      }

      // reduce 16 K-slices (sbuf reused as red[16][32][17])
#pragma unroll
      for (int cc = 0; cc < kCPB; ++cc)
        sbuf[(s_ * kB + bb) * kCPB + cc] = acc[cc];
      __syncthreads();
      for (int o = tid; o < kB * kCPB; o += kNTHR) {
        int cc = o >> 5;
        int br = o & 31;
        float sum = 0.f;
#pragma unroll
        for (int s2 = 0; s2 < 16; ++s2)
          sum += sbuf[(s2 * kB + br) * kCPB + cc];
        int j = j0 + cc;
        float bias = (j < 4 * kH) ? bl[j] : bv[j - 4 * kH];
        gates[(size_t)br * kNG + j] = sum + bias;   // plain store; fence flushes
      }
      gridbar();

      // ========== Phase B: master gates + cell update ==========
      {
        const int pb    = bid >> 3;
        const int chunk = bid & 7;
        const float* gr = gates + (size_t)pb * kNG;
        const int lane = tid & 63, wv2 = tid >> 6;
        const bool act = tid < 128;

        float ai = 0.f, af = 0.f;
        if (act) { ai = ld_coh(gr + 4096 + tid); af = ld_coh(gr + 4096 + kLV + tid); }
        float mi = ai, mf = af;
        if (act) {
#pragma unroll
          for (int d2 = 32; d2 > 0; d2 >>= 1) {
            mi = fmaxf(mi, __shfl_xor(mi, d2));
            mf = fmaxf(mf, __shfl_xor(mf, d2));
          }
          if (lane == 0) { smx[wv2] = mi; smx[2 + wv2] = mf; }
        }
        __syncthreads();
        mi = fmaxf(smx[0], smx[1]);
        mf = fmaxf(smx[2], smx[3]);
        float ei = 0.f, ef = 0.f, Pi = 0.f, Pf = 0.f;
        if (act) {
          ei = __expf(ai - mi); ef = __expf(af - mf);
          Pi = ei; Pf = ef;
#pragma unroll
          for (int d2 = 1; d2 < 64; d2 <<= 1) {
            float ni = __shfl_up(Pi, d2);
            float nf = __shfl_up(Pf, d2);
            if (lane >= d2) { Pi += ni; Pf += nf; }
          }
          if (lane == 63) { smx[4 + wv2] = Pi; smx[6 + wv2] = Pf; }
        }
        __syncthreads();
        float Si = smx[4] + smx[5], Sf = smx[6] + smx[7];
        if (act) {
          if (wv2 == 1) { Pi += smx[4]; Pf += smx[6]; }
          ih_sh[tid] = Pf / Sf;                  // cumsum(softmax(cc_f_h))
          fh_sh[tid] = (Si - Pi + ei) / Si;      // rev-cumsum(softmax(rev cc_i_h))
        }
        __syncthreads();
        if (act) {
          int j = chunk * 128 + tid;
          float vi = ld_coh(gr + j);
          float vf = ld_coh(gr + kH + j);
          float vo = ld_coh(gr + 2 * kH + j);
          float vg = ld_coh(gr + 3 * kH + j);
          float i_ = 1.f / (1.f + __expf(-vi));
          float f_ = 1.f / (1.f + __expf(-vf));
          float o_ = 1.f / (1.f + __expf(-vo));
          float g_ = tanhf(vg);
          int l2 = j >> 3;
          float ih = ih_sh[l2], fh = fh_sh[l2];
          float w  = ih * fh;
          float cold = creg;
          float cn = w * (f_ * cold + i_ * g_) + (fh - w) * cold + (ih - w) * g_;
          float hn = o_ * tanhf(cn);
          creg = cn;
          h[(size_t)pb * kH + j] = hn;                        // plain + fence
          out[((size_t)pb * kT + t) * kH + j] = hn;           // plain + fence
        }
      }
      gridbar();
    }
  }
}

extern "C" void kernel_launch(void* const* d_in, const int* in_sizes, int n_in,
                              void* d_out, int out_size, void* d_ws, size_t ws_size,
                              hipStream_t stream) {
  const float* x   = (const float*)d_in[0];
  const float* Wl0 = (const float*)d_in[1];
  const float* bl0 = (const float*)d_in[2];
  const float* Wv0 = (const float*)d_in[3];
  const float* bv0 = (const float*)d_in[4];
  const float* Wl1 = (const float*)d_in[5];
  const float* bl1 = (const float*)d_in[6];
  const float* Wv1 = (const float*)d_in[7];
  const float* bv1 = (const float*)d_in[8];
  (void)in_sizes; (void)n_in; (void)out_size; (void)ws_size;

  onlstm_kernel<<<dim3(kNBLK), dim3(kNTHR), 0, stream>>>(
      x, Wl0, bl0, Wv0, bv0, Wl1, bl1, Wv1, bv1,
      (float*)d_out, (float*)d_ws);
}

// Round 5
// 93141.766 us; speedup vs baseline: 1.4471x; 1.1354x over previous
//
#include <hip/hip_runtime.h>

namespace {
constexpr int kB  = 32;
constexpr int kT  = 1024;
constexpr int kD  = 512;
constexpr int kH  = 1024;
constexpr int kLV = 128;
constexpr int kNG = 4 * kH + 2 * kLV;   // 4352
constexpr int kNBLK = 256;
constexpr int kNTHR = 512;
constexpr int kBK   = 256;
constexpr int kSTR  = kBK + 4;          // 260
constexpr int kCPB  = 34;               // 32 lstm + 2 lvl cols per A-block
}

typedef float vfloat4 __attribute__((ext_vector_type(4)));

static __device__ __forceinline__ unsigned ld_flag(const unsigned* p) {
  return __hip_atomic_load(p, __ATOMIC_RELAXED, __HIP_MEMORY_SCOPE_AGENT);
}
static __device__ __forceinline__ void st_flag(unsigned* p, unsigned v) {
  __hip_atomic_store(p, v, __ATOMIC_RELAXED, __HIP_MEMORY_SCOPE_AGENT);
}
static __device__ __forceinline__ float ld_coh(const float* p) {
  return __hip_atomic_load(p, __ATOMIC_RELAXED, __HIP_MEMORY_SCOPE_AGENT);
}
// 4 coherent 16B loads, overlapped, completed INSIDE one asm (no in-flight
// asm outputs visible to the register allocator -> no spill/copy hazard).
static __device__ __forceinline__ void ld_sc_x4(vfloat4 v[4],
    const float* p0, const float* p1, const float* p2, const float* p3) {
  asm volatile(
      "global_load_dwordx4 %0, %4, off sc0 sc1\n\t"
      "global_load_dwordx4 %1, %5, off sc0 sc1\n\t"
      "global_load_dwordx4 %2, %6, off sc0 sc1\n\t"
      "global_load_dwordx4 %3, %7, off sc0 sc1\n\t"
      "s_waitcnt vmcnt(0)"
      : "=&v"(v[0]), "=&v"(v[1]), "=&v"(v[2]), "=&v"(v[3])
      : "v"(p0), "v"(p1), "v"(p2), "v"(p3)
      : "memory");
}

__global__ __launch_bounds__(kNTHR, 2) void onlstm_kernel(
    const float* __restrict__ x,
    const float* __restrict__ Wl0, const float* __restrict__ bl0,
    const float* __restrict__ Wv0, const float* __restrict__ bv0,
    const float* __restrict__ Wl1, const float* __restrict__ bl1,
    const float* __restrict__ Wv1, const float* __restrict__ bv1,
    float* __restrict__ out, float* __restrict__ ws)
{
  const int tid = threadIdx.x;
  const int bid = blockIdx.x;

  // ---- workspace ----
  unsigned* flags = (unsigned*)ws;            // [256] stride-16 uints
  unsigned* genp  = (unsigned*)ws + 4096;
  float* h0     = ws + 8192;                  // [32][1024]
  float* h1     = h0 + kB * kH;
  float* gates0 = h1 + kB * kH;               // [32][4352]
  float* gates1 = gates0 + kB * kNG;

  __shared__ float sbuf[16 * kB * kCPB];      // 69,632 B; comb overlay [32][260]
  __shared__ float ih_sh[kLV], fh_sh[kLV];
  __shared__ float smx[8];

  unsigned seq = 0;
  auto gridbar = [&]() {                      // round-2-proven shape
    ++seq;
    __syncthreads();                          // implies vmcnt drain
    if (tid == 0) __builtin_amdgcn_fence(__ATOMIC_RELEASE, "agent");
    if (bid == 0) {
      if (tid >= 1 && tid < kNBLK) {
        while (ld_flag(&flags[tid * 16]) != seq) __builtin_amdgcn_s_sleep(2);
      }
      __syncthreads();
      if (tid == 0) st_flag(genp, seq);
    } else {
      if (tid == 0) {
        st_flag(&flags[bid * 16], seq);
        while (ld_flag(genp) != seq) __builtin_amdgcn_s_sleep(2);
      }
      __syncthreads();
    }
    asm volatile("" ::: "memory");
  };

  // ---- roles ----
  const int role = bid >> 7;                  // 0: layer0, 1: layer1
  const int g    = bid & 127;
  const int IN   = role ? kH : kD;
  const int K    = IN + kH;
  const int nchunk = K / kBK;                 // 6 or 8
  const float* Wl = role ? Wl1 : Wl0;
  const float* Wv = role ? Wv1 : Wv0;
  const float* bl = role ? bl1 : bl0;
  const float* bv = role ? bv1 : bv0;
  float* gates = role ? gates1 : gates0;
  float* hbuf  = role ? h1 : h0;
  const float* xin = role ? out : x;
  const float* pWl = Wl + (size_t)(g * 32) * K;
  const float* pWv = Wv + (size_t)(g * 2) * K;

  const int s_ = tid >> 5;                    // K-slice 0..15
  const int bb = tid & 31;                    // batch row
  const int pb = g >> 2;                      // phase-B row
  const int qq4 = g & 3;                      // phase-B col quarter

  // zero h0,h1 (plain stores; fence in gridbar flushes to coherent point)
  {
    int idx = bid * kNTHR + tid;
    if (idx < 2 * kB * kH) h0[idx] = 0.f;
  }
  float creg = 0.f;
  gridbar();

  float acc[kCPB];

  for (int e = 0; e <= kT; ++e) {
    const bool act = (role == 0) ? (e < kT) : (e >= 1);
    const int t = (role == 0) ? e : e - 1;

    // ========== Phase A: gates = [x_t, h] @ W^T + b ==========
    if (act) {
#pragma unroll
      for (int cc = 0; cc < kCPB; ++cc) acc[cc] = 0.f;

      for (int kc = 0; kc < nchunk; ++kc) {
        const int kbase = kc * kBK;
        vfloat4 v[4];
        const float* ps[4];
#pragma unroll
        for (int it = 0; it < 4; ++it) {
          int fq = it * kNTHR + tid;          // 0..2047 quads
          int br = fq >> 6, qw = fq & 63;
          int k = kbase + qw * 4;
          ps[it] = (k < IN) ? (xin + ((size_t)br * kT + t) * IN + k)
                            : (hbuf + br * kH + (k - IN));
        }
        if (role == 0 && kbase < IN) {        // pure-x chunk: immutable, plain
#pragma unroll
          for (int it = 0; it < 4; ++it) v[it] = *(const vfloat4*)ps[it];
        } else {                              // mutable (out or h): coherent
          ld_sc_x4(v, ps[0], ps[1], ps[2], ps[3]);
        }
#pragma unroll
        for (int it = 0; it < 4; ++it) {
          int fq = it * kNTHR + tid;
          int br = fq >> 6, qw = fq & 63;
          *(vfloat4*)&sbuf[br * kSTR + qw * 4] = v[it];
        }
        __syncthreads();

        const float* cb = &sbuf[bb * kSTR + s_ * 16];
#pragma unroll
        for (int q8 = 0; q8 < 4; ++q8) {
          vfloat4 cv = *(const vfloat4*)&cb[q8 * 4];
          const int ko = kbase + s_ * 16 + q8 * 4;
#pragma unroll
          for (int cc = 0; cc < kCPB; ++cc) {
            const float* wp = (cc < 32) ? (pWl + (size_t)cc * K + ko)
                                        : (pWv + (size_t)(cc - 32) * K + ko);
            vfloat4 wv = *(const vfloat4*)wp;
            acc[cc] = fmaf(cv.x, wv.x, acc[cc]);
            acc[cc] = fmaf(cv.y, wv.y, acc[cc]);
            acc[cc] = fmaf(cv.z, wv.z, acc[cc]);
            acc[cc] = fmaf(cv.w, wv.w, acc[cc]);
          }
        }
        __syncthreads();
      }

      // reduce 16 K-slices via LDS (sbuf overlay [16][32][34])
#pragma unroll
      for (int cc = 0; cc < kCPB; ++cc)
        sbuf[(s_ * kB + bb) * kCPB + cc] = acc[cc];
      __syncthreads();
      for (int o = tid; o < kB * kCPB; o += kNTHR) {
        int br = o / kCPB;
        int cc = o - br * kCPB;
        float sum = 0.f;
#pragma unroll
        for (int s2 = 0; s2 < 16; ++s2)
          sum += sbuf[(s2 * kB + br) * kCPB + cc];
        int j = (cc < 32) ? (g * 32 + cc) : (4096 + g * 2 + (cc - 32));
        float bias = (cc < 32) ? bl[g * 32 + cc] : bv[g * 2 + (cc - 32)];
        gates[(size_t)br * kNG + j] = sum + bias;   // plain; fence flushes
      }
    }
    gridbar();

    // ========== Phase B: master gates + cell update ==========
    if (act) {
      const float* gr = gates + (size_t)pb * kNG;
      const int lane = tid & 63, wv2 = tid >> 6;
      const bool sm = tid < 128;
      const bool cl = tid < 256;

      float vi = 0.f, vf = 0.f, vo = 0.f, vg = 0.f;
      int j = qq4 * 256 + tid;
      if (cl) {                               // hoisted: latency under softmax
        vi = ld_coh(gr + j);
        vf = ld_coh(gr + kH + j);
        vo = ld_coh(gr + 2 * kH + j);
        vg = ld_coh(gr + 3 * kH + j);
      }

      float ai = 0.f, af = 0.f;
      if (sm) { ai = ld_coh(gr + 4096 + tid); af = ld_coh(gr + 4096 + kLV + tid); }
      float mi = ai, mf = af;
      if (sm) {
#pragma unroll
        for (int d2 = 32; d2 > 0; d2 >>= 1) {
          mi = fmaxf(mi, __shfl_xor(mi, d2));
          mf = fmaxf(mf, __shfl_xor(mf, d2));
        }
        if (lane == 0) { smx[wv2] = mi; smx[2 + wv2] = mf; }
      }
      __syncthreads();
      mi = fmaxf(smx[0], smx[1]);
      mf = fmaxf(smx[2], smx[3]);
      float ei = 0.f, Pi = 0.f, Pf = 0.f;
      if (sm) {
        ei = __expf(ai - mi);
        float ef = __expf(af - mf);
        Pi = ei; Pf = ef;
#pragma unroll
        for (int d2 = 1; d2 < 64; d2 <<= 1) {
          float ni = __shfl_up(Pi, d2);
          float nf = __shfl_up(Pf, d2);
          if (lane >= d2) { Pi += ni; Pf += nf; }
        }
        if (lane == 63) { smx[4 + wv2] = Pi; smx[6 + wv2] = Pf; }
      }
      __syncthreads();
      float Si = smx[4] + smx[5], Sf = smx[6] + smx[7];
      if (sm) {
        if (wv2 == 1) { Pi += smx[4]; Pf += smx[6]; }
        ih_sh[tid] = Pf / Sf;                 // cumsum(softmax(cc_f_h))
        fh_sh[tid] = (Si - Pi + ei) / Si;     // rev-cumsum(softmax(rev cc_i_h))
      }
      __syncthreads();
      if (cl) {
        float i_ = 1.f / (1.f + __expf(-vi));
        float f_ = 1.f / (1.f + __expf(-vf));
        float o_ = 1.f / (1.f + __expf(-vo));
        float g_ = tanhf(vg);
        int l2 = j >> 3;
        float ih = ih_sh[l2], fh = fh_sh[l2];
        float w  = ih * fh;
        float cold = creg;
        float cn = w * (f_ * cold + i_ * g_) + (fh - w) * cold + (ih - w) * g_;
        float hn = o_ * tanhf(cn);
        creg = cn;
        hbuf[(size_t)pb * kH + j] = hn;                  // plain; fence flushes
        out[((size_t)pb * kT + t) * kH + j] = hn;        // plain; fence flushes
      }
    }
    gridbar();
  }
}

extern "C" void kernel_launch(void* const* d_in, const int* in_sizes, int n_in,
                              void* d_out, int out_size, void* d_ws, size_t ws_size,
                              hipStream_t stream) {
  const float* x   = (const float*)d_in[0];
  const float* Wl0 = (const float*)d_in[1];
  const float* bl0 = (const float*)d_in[2];
  const float* Wv0 = (const float*)d_in[3];
  const float* bv0 = (const float*)d_in[4];
  const float* Wl1 = (const float*)d_in[5];
  const float* bl1 = (const float*)d_in[6];
  const float* Wv1 = (const float*)d_in[7];
  const float* bv1 = (const float*)d_in[8];
  (void)in_sizes; (void)n_in; (void)out_size; (void)ws_size;

  onlstm_kernel<<<dim3(kNBLK), dim3(kNTHR), 0, stream>>>(
      x, Wl0, bl0, Wv0, bv0, Wl1, bl1, Wv1, bv1,
      (float*)d_out, (float*)d_ws);
}

// Round 6
// 60531.433 us; speedup vs baseline: 2.2268x; 1.5387x over previous
//
#include <hip/hip_runtime.h>

namespace {
constexpr int kB  = 32;
constexpr int kT  = 1024;
constexpr int kD  = 512;
constexpr int kH  = 1024;
constexpr int kLV = 128;
constexpr int kNG = 4 * kH + 2 * kLV;   // 4352
constexpr int kNBLK = 256;
constexpr int kNTHR = 512;
constexpr int kBK   = 512;              // K-chunk (aligns with x/h segments)
constexpr int kRowB = 1032;             // comb LDS row stride in BYTES (516 halfs)
constexpr int kCPB  = 34;               // 32 lstm + 2 lvl cols per A-block
// ws float offsets
constexpr int kOffH0 = 8192;
constexpr int kOffWF = kOffH0 + 2 * kB * kH + 2 * kB * kNG;  // = 352256
}

typedef float vfloat4 __attribute__((ext_vector_type(4)));
typedef _Float16 half2_t __attribute__((ext_vector_type(2)));
typedef _Float16 half8_t __attribute__((ext_vector_type(8)));
typedef unsigned short ushort_t;

static __device__ __forceinline__ unsigned ld_flag(const unsigned* p) {
  return __hip_atomic_load(p, __ATOMIC_RELAXED, __HIP_MEMORY_SCOPE_AGENT);
}
static __device__ __forceinline__ void st_flag(unsigned* p, unsigned v) {
  __hip_atomic_store(p, v, __ATOMIC_RELAXED, __HIP_MEMORY_SCOPE_AGENT);
}
static __device__ __forceinline__ float ld_coh(const float* p) {
  return __hip_atomic_load(p, __ATOMIC_RELAXED, __HIP_MEMORY_SCOPE_AGENT);
}
// 8 coherent 16B loads, overlapped, completed INSIDE one asm block.
static __device__ __forceinline__ void ld_sc_x8(vfloat4 v[8],
    const float* p0, const float* p1, const float* p2, const float* p3,
    const float* p4, const float* p5, const float* p6, const float* p7) {
  asm volatile(
      "global_load_dwordx4 %0, %8, off sc0 sc1\n\t"
      "global_load_dwordx4 %1, %9, off sc0 sc1\n\t"
      "global_load_dwordx4 %2, %10, off sc0 sc1\n\t"
      "global_load_dwordx4 %3, %11, off sc0 sc1\n\t"
      "global_load_dwordx4 %4, %12, off sc0 sc1\n\t"
      "global_load_dwordx4 %5, %13, off sc0 sc1\n\t"
      "global_load_dwordx4 %6, %14, off sc0 sc1\n\t"
      "global_load_dwordx4 %7, %15, off sc0 sc1\n\t"
      "s_waitcnt vmcnt(0)"
      : "=&v"(v[0]), "=&v"(v[1]), "=&v"(v[2]), "=&v"(v[3]),
        "=&v"(v[4]), "=&v"(v[5]), "=&v"(v[6]), "=&v"(v[7])
      : "v"(p0), "v"(p1), "v"(p2), "v"(p3), "v"(p4), "v"(p5), "v"(p6), "v"(p7)
      : "memory");
}
static __device__ __forceinline__ float fdot2(unsigned a, unsigned b, float c) {
  return __builtin_amdgcn_fdot2(__builtin_bit_cast(half2_t, a),
                                __builtin_bit_cast(half2_t, b), c, false);
}

// -------- fp32 -> fp16 weight conversion (one-time pre-pass) --------
__global__ __launch_bounds__(256) void cvt_fp16_kernel(
    const float* __restrict__ src, ushort_t* __restrict__ dst, int n8) {
  int i = blockIdx.x * 256 + threadIdx.x;
  if (i >= n8) return;
  const vfloat4* s4 = (const vfloat4*)src;
  vfloat4 a = s4[2 * i], b = s4[2 * i + 1];
  half8_t o;
  o[0] = (_Float16)a.x; o[1] = (_Float16)a.y;
  o[2] = (_Float16)a.z; o[3] = (_Float16)a.w;
  o[4] = (_Float16)b.x; o[5] = (_Float16)b.y;
  o[6] = (_Float16)b.z; o[7] = (_Float16)b.w;
  ((half8_t*)dst)[i] = o;
}

__global__ __launch_bounds__(kNTHR, 2) void onlstm_kernel(
    const float* __restrict__ x,
    const float* __restrict__ bl0, const float* __restrict__ bv0,
    const float* __restrict__ bl1, const float* __restrict__ bv1,
    const ushort_t* __restrict__ wf0u, const ushort_t* __restrict__ wf1u,
    float* __restrict__ out, float* __restrict__ ws)
{
  const int tid = threadIdx.x;
  const int bid = blockIdx.x;

  // ---- workspace ----
  unsigned* flags = (unsigned*)ws;            // [256] stride-16 uints
  unsigned* genp  = (unsigned*)ws + 4096;
  float* h0     = ws + kOffH0;                // [32][1024]
  float* h1     = h0 + kB * kH;
  float* gates0 = h1 + kB * kH;               // [32][4352]
  float* gates1 = gates0 + kB * kNG;

  __shared__ float sbuf[16 * kB * kCPB];      // 69,632 B; comb overlay 33,024 B
  __shared__ float ih_sh[kLV], fh_sh[kLV];
  __shared__ float smx[8];

  unsigned seq = 0;
  auto gridbar = [&]() {                      // round-2/5-proven shape
    ++seq;
    __syncthreads();
    if (tid == 0) __builtin_amdgcn_fence(__ATOMIC_RELEASE, "agent");
    if (bid == 0) {
      if (tid >= 1 && tid < kNBLK) {
        while (ld_flag(&flags[tid * 16]) != seq) __builtin_amdgcn_s_sleep(2);
      }
      __syncthreads();
      if (tid == 0) st_flag(genp, seq);
    } else {
      if (tid == 0) {
        st_flag(&flags[bid * 16], seq);
        while (ld_flag(genp) != seq) __builtin_amdgcn_s_sleep(2);
      }
      __syncthreads();
    }
    asm volatile("" ::: "memory");
  };

  // ---- roles ----
  const int role = bid >> 7;                  // 0: layer0, 1: layer1
  const int g    = bid & 127;
  const int IN   = role ? kH : kD;
  const int K    = IN + kH;
  const int nchunk = K / kBK;                 // 3 or 4
  const float* bl = role ? bl1 : bl0;
  const float* bv = role ? bv1 : bv0;
  float* gates = role ? gates1 : gates0;
  float* hbuf  = role ? h1 : h0;
  const float* xin = role ? out : x;
  const _Float16* wf = (const _Float16*)(role ? wf1u : wf0u);

  const int s_ = tid >> 5;                    // K-slice 0..15 (32 halfs each)
  const int bb = tid & 31;                    // batch row
  const int pb = g >> 2;                      // phase-B row
  const int qq4 = g & 3;                      // phase-B col quarter

  // per-block fp16 weight row pointers (block-uniform)
  const _Float16* wrow16[kCPB];
#pragma unroll
  for (int cc = 0; cc < kCPB; ++cc) {
    int j = (cc < 32) ? (g * 32 + cc) : (4096 + g * 2 + (cc - 32));
    wrow16[cc] = wf + (size_t)j * K;
  }

  // zero h0,h1
  {
    int idx = bid * kNTHR + tid;
    if (idx < 2 * kB * kH) h0[idx] = 0.f;
  }
  float creg = 0.f;
  gridbar();

  float acc[kCPB];

  for (int e = 0; e <= kT; ++e) {
    const bool act = (role == 0) ? (e < kT) : (e >= 1);
    const int t = (role == 0) ? e : e - 1;

    // ========== Phase A: gates = [x_t, h] @ W^T + b (fp16 dot2) ==========
    if (act) {
#pragma unroll
      for (int cc = 0; cc < kCPB; ++cc) acc[cc] = 0.f;

      for (int kc = 0; kc < nchunk; ++kc) {
        const int kbase = kc * kBK;
        const bool xside = (kbase < IN);      // chunk fully x-side or h-side
        vfloat4 v[8];
        const float* ps[8];
#pragma unroll
        for (int it = 0; it < 8; ++it) {
          int fq = it * kNTHR + tid;          // 0..4095 quads
          int br = fq >> 7, qw = fq & 127;
          int k = kbase + qw * 4;
          ps[it] = xside ? (xin + ((size_t)br * kT + t) * IN + k)
                         : (hbuf + br * kH + (k - IN));
        }
        if (role == 0 && xside) {             // x: immutable, plain cached
#pragma unroll
          for (int it = 0; it < 8; ++it) v[it] = *(const vfloat4*)ps[it];
        } else {                              // mutable (out or h): coherent
          ld_sc_x8(v, ps[0], ps[1], ps[2], ps[3], ps[4], ps[5], ps[6], ps[7]);
        }
        // convert to fp16 and stage into LDS
#pragma unroll
        for (int it = 0; it < 8; ++it) {
          int fq = it * kNTHR + tid;
          int br = fq >> 7, qw = fq & 127;
          uint2 pk;
          pk.x = __builtin_bit_cast(unsigned,
                   __builtin_amdgcn_cvt_pkrtz(v[it].x, v[it].y));
          pk.y = __builtin_bit_cast(unsigned,
                   __builtin_amdgcn_cvt_pkrtz(v[it].z, v[it].w));
          *(uint2*)((char*)sbuf + br * kRowB + qw * 8) = pk;
        }
        __syncthreads();

        // read own comb slice (32 halfs) from LDS
        uint2 cb[8];
        const char* cp = (const char*)sbuf + bb * kRowB + s_ * 64;
#pragma unroll
        for (int r = 0; r < 8; ++r) cb[r] = *(const uint2*)(cp + r * 8);

        // 34 cols x 16 dot2 (weights from L2-resident fp16)
#pragma unroll
        for (int cc = 0; cc < kCPB; ++cc) {
          const _Float16* wp = wrow16[cc] + kbase + s_ * 32;
          uint4 wa = *(const uint4*)wp;
          uint4 wb = *(const uint4*)(wp + 8);
          uint4 wc = *(const uint4*)(wp + 16);
          uint4 wd = *(const uint4*)(wp + 24);
          float a = acc[cc];
          a = fdot2(cb[0].x, wa.x, a); a = fdot2(cb[0].y, wa.y, a);
          a = fdot2(cb[1].x, wa.z, a); a = fdot2(cb[1].y, wa.w, a);
          a = fdot2(cb[2].x, wb.x, a); a = fdot2(cb[2].y, wb.y, a);
          a = fdot2(cb[3].x, wb.z, a); a = fdot2(cb[3].y, wb.w, a);
          a = fdot2(cb[4].x, wc.x, a); a = fdot2(cb[4].y, wc.y, a);
          a = fdot2(cb[5].x, wc.z, a); a = fdot2(cb[5].y, wc.w, a);
          a = fdot2(cb[6].x, wd.x, a); a = fdot2(cb[6].y, wd.y, a);
          a = fdot2(cb[7].x, wd.z, a); a = fdot2(cb[7].y, wd.w, a);
          acc[cc] = a;
        }
        __syncthreads();
      }

      // reduce 16 K-slices via LDS (overlay float[16][32][34])
#pragma unroll
      for (int cc = 0; cc < kCPB; ++cc)
        sbuf[(s_ * kB + bb) * kCPB + cc] = acc[cc];
      __syncthreads();
      for (int o = tid; o < kB * kCPB; o += kNTHR) {
        int br = o / kCPB;
        int cc = o - br * kCPB;
        float sum = 0.f;
#pragma unroll
        for (int s2 = 0; s2 < 16; ++s2)
          sum += sbuf[(s2 * kB + br) * kCPB + cc];
        int j = (cc < 32) ? (g * 32 + cc) : (4096 + g * 2 + (cc - 32));
        float bias = (cc < 32) ? bl[g * 32 + cc] : bv[g * 2 + (cc - 32)];
        gates[(size_t)br * kNG + j] = sum + bias;   // plain; fence flushes
      }
    }
    gridbar();

    // ========== Phase B: master gates + cell update ==========
    if (act) {
      const float* gr = gates + (size_t)pb * kNG;
      const int lane = tid & 63, wv2 = tid >> 6;
      const bool sm = tid < 128;
      const bool cl = tid < 256;

      float vi = 0.f, vf = 0.f, vo = 0.f, vg = 0.f;
      int j = qq4 * 256 + tid;
      if (cl) {                               // hoisted: latency under softmax
        vi = ld_coh(gr + j);
        vf = ld_coh(gr + kH + j);
        vo = ld_coh(gr + 2 * kH + j);
        vg = ld_coh(gr + 3 * kH + j);
      }

      float ai = 0.f, af = 0.f;
      if (sm) { ai = ld_coh(gr + 4096 + tid); af = ld_coh(gr + 4096 + kLV + tid); }
      float mi = ai, mf = af;
      if (sm) {
#pragma unroll
        for (int d2 = 32; d2 > 0; d2 >>= 1) {
          mi = fmaxf(mi, __shfl_xor(mi, d2));
          mf = fmaxf(mf, __shfl_xor(mf, d2));
        }
        if (lane == 0) { smx[wv2] = mi; smx[2 + wv2] = mf; }
      }
      __syncthreads();
      mi = fmaxf(smx[0], smx[1]);
      mf = fmaxf(smx[2], smx[3]);
      float ei = 0.f, Pi = 0.f, Pf = 0.f;
      if (sm) {
        ei = __expf(ai - mi);
        float ef = __expf(af - mf);
        Pi = ei; Pf = ef;
#pragma unroll
        for (int d2 = 1; d2 < 64; d2 <<= 1) {
          float ni = __shfl_up(Pi, d2);
          float nf = __shfl_up(Pf, d2);
          if (lane >= d2) { Pi += ni; Pf += nf; }
        }
        if (lane == 63) { smx[4 + wv2] = Pi; smx[6 + wv2] = Pf; }
      }
      __syncthreads();
      float Si = smx[4] + smx[5], Sf = smx[6] + smx[7];
      if (sm) {
        if (wv2 == 1) { Pi += smx[4]; Pf += smx[6]; }
        ih_sh[tid] = Pf / Sf;                 // cumsum(softmax(cc_f_h))
        fh_sh[tid] = (Si - Pi + ei) / Si;     // rev-cumsum(softmax(rev cc_i_h))
      }
      __syncthreads();
      if (cl) {
        float i_ = 1.f / (1.f + __expf(-vi));
        float f_ = 1.f / (1.f + __expf(-vf));
        float o_ = 1.f / (1.f + __expf(-vo));
        float g_ = tanhf(vg);
        int l2 = j >> 3;
        float ih = ih_sh[l2], fh = fh_sh[l2];
        float w  = ih * fh;
        float cold = creg;
        float cn = w * (f_ * cold + i_ * g_) + (fh - w) * cold + (ih - w) * g_;
        float hn = o_ * tanhf(cn);
        creg = cn;
        hbuf[(size_t)pb * kH + j] = hn;                  // plain; fence flushes
        out[((size_t)pb * kT + t) * kH + j] = hn;        // plain; fence flushes
      }
    }
    gridbar();
  }
}

extern "C" void kernel_launch(void* const* d_in, const int* in_sizes, int n_in,
                              void* d_out, int out_size, void* d_ws, size_t ws_size,
                              hipStream_t stream) {
  const float* x   = (const float*)d_in[0];
  const float* Wl0 = (const float*)d_in[1];
  const float* bl0 = (const float*)d_in[2];
  const float* Wv0 = (const float*)d_in[3];
  const float* bv0 = (const float*)d_in[4];
  const float* Wl1 = (const float*)d_in[5];
  const float* bl1 = (const float*)d_in[6];
  const float* Wv1 = (const float*)d_in[7];
  const float* bv1 = (const float*)d_in[8];
  (void)in_sizes; (void)n_in; (void)out_size; (void)ws_size;

  float* ws = (float*)d_ws;
  ushort_t* wf0 = (ushort_t*)(ws + kOffWF);                 // [4352][1536] fp16
  ushort_t* wf1 = wf0 + (size_t)4352 * 1536;                // [4352][2048] fp16

  // pre-pass: convert weights to fp16 (Wl then Wv rows, per layer)
  {
    int n;
    n = 4096 * 1536 / 8;
    cvt_fp16_kernel<<<(n + 255) / 256, 256, 0, stream>>>(Wl0, wf0, n);
    n = 256 * 1536 / 8;
    cvt_fp16_kernel<<<(n + 255) / 256, 256, 0, stream>>>(
        Wv0, wf0 + (size_t)4096 * 1536, n);
    n = 4096 * 2048 / 8;
    cvt_fp16_kernel<<<(n + 255) / 256, 256, 0, stream>>>(Wl1, wf1, n);
    n = 256 * 2048 / 8;
    cvt_fp16_kernel<<<(n + 255) / 256, 256, 0, stream>>>(
        Wv1, wf1 + (size_t)4096 * 2048, n);
  }

  onlstm_kernel<<<dim3(kNBLK), dim3(kNTHR), 0, stream>>>(
      x, bl0, bv0, bl1, bv1, wf0, wf1, (float*)d_out, ws);
}

// Round 7
// 41328.674 us; speedup vs baseline: 3.2614x; 1.4646x over previous
//
#include <hip/hip_runtime.h>

namespace {
constexpr int kB  = 32;
constexpr int kT  = 1024;
constexpr int kD  = 512;
constexpr int kH  = 1024;
constexpr int kLV = 128;
constexpr int kNG = 4 * kH + 2 * kLV;   // 4352
constexpr int kNBLK = 256;
constexpr int kNTHR = 512;
constexpr int kCPB  = 34;               // 32 lstm + 2 lvl cols per A-block
// ws float offsets
constexpr int kOffH0 = 8192;
constexpr int kOffWF = kOffH0 + 2 * kB * kH + 2 * kB * kNG;
}

typedef float vfloat4 __attribute__((ext_vector_type(4)));
typedef _Float16 half2_t __attribute__((ext_vector_type(2)));
typedef _Float16 half8_t __attribute__((ext_vector_type(8)));
typedef unsigned short ushort_t;

static __device__ __forceinline__ unsigned ld_flag(const unsigned* p) {
  return __hip_atomic_load(p, __ATOMIC_RELAXED, __HIP_MEMORY_SCOPE_AGENT);
}
static __device__ __forceinline__ void st_flag(unsigned* p, unsigned v) {
  __hip_atomic_store(p, v, __ATOMIC_RELAXED, __HIP_MEMORY_SCOPE_AGENT);
}
static __device__ __forceinline__ float ld_coh(const float* p) {
  return __hip_atomic_load(p, __ATOMIC_RELAXED, __HIP_MEMORY_SCOPE_AGENT);
}
// 8 coherent 16B loads, overlapped, completed INSIDE one asm block (proven r5/r6).
static __device__ __forceinline__ void ld_sc_x8(vfloat4 v[8], const float* b) {
  asm volatile(
      "global_load_dwordx4 %0, %8, off sc0 sc1\n\t"
      "global_load_dwordx4 %1, %9, off sc0 sc1\n\t"
      "global_load_dwordx4 %2, %10, off sc0 sc1\n\t"
      "global_load_dwordx4 %3, %11, off sc0 sc1\n\t"
      "global_load_dwordx4 %4, %12, off sc0 sc1\n\t"
      "global_load_dwordx4 %5, %13, off sc0 sc1\n\t"
      "global_load_dwordx4 %6, %14, off sc0 sc1\n\t"
      "global_load_dwordx4 %7, %15, off sc0 sc1\n\t"
      "s_waitcnt vmcnt(0)"
      : "=&v"(v[0]), "=&v"(v[1]), "=&v"(v[2]), "=&v"(v[3]),
        "=&v"(v[4]), "=&v"(v[5]), "=&v"(v[6]), "=&v"(v[7])
      : "v"(b), "v"(b + 4), "v"(b + 8), "v"(b + 12),
        "v"(b + 16), "v"(b + 20), "v"(b + 24), "v"(b + 28)
      : "memory");
}
static __device__ __forceinline__ float fdot2(unsigned a, unsigned b, float c) {
  return __builtin_amdgcn_fdot2(__builtin_bit_cast(half2_t, a),
                                __builtin_bit_cast(half2_t, b), c, false);
}
static __device__ __forceinline__ unsigned pkrtz(float a, float b) {
  return __builtin_bit_cast(unsigned, __builtin_amdgcn_cvt_pkrtz(a, b));
}

// -------- fp32 -> fp16 weight conversion (one-time pre-pass) --------
__global__ __launch_bounds__(256) void cvt_fp16_kernel(
    const float* __restrict__ src, ushort_t* __restrict__ dst, int n8) {
  int i = blockIdx.x * 256 + threadIdx.x;
  if (i >= n8) return;
  const vfloat4* s4 = (const vfloat4*)src;
  vfloat4 a = s4[2 * i], b = s4[2 * i + 1];
  half8_t o;
  o[0] = (_Float16)a.x; o[1] = (_Float16)a.y;
  o[2] = (_Float16)a.z; o[3] = (_Float16)a.w;
  o[4] = (_Float16)b.x; o[5] = (_Float16)b.y;
  o[6] = (_Float16)b.z; o[7] = (_Float16)b.w;
  ((half8_t*)dst)[i] = o;
}

__global__ __launch_bounds__(kNTHR, 2) void onlstm_kernel(
    const float* __restrict__ x,
    const float* __restrict__ bl0, const float* __restrict__ bv0,
    const float* __restrict__ bl1, const float* __restrict__ bv1,
    const ushort_t* __restrict__ wf0u, const ushort_t* __restrict__ wf1u,
    float* __restrict__ out, float* __restrict__ ws)
{
  const int tid = threadIdx.x;
  const int bid = blockIdx.x;

  // ---- workspace ----
  unsigned* flags = (unsigned*)ws;            // [256] stride-16 uints
  unsigned* genp  = (unsigned*)ws + 4096;
  float* h0     = ws + kOffH0;                // [32][1024]
  float* h1     = h0 + kB * kH;
  float* gates0 = h1 + kB * kH;               // [32][4352]
  float* gates1 = gates0 + kB * kNG;

  // LDS: weights as 16B granules, permuted (p = j*16 + s within each 512-k seg)
  __shared__ uint4 wlds4[kCPB * 256];         // 139,264 B (L1 needs all, L0 3/4)
  __shared__ float ih_sh[kLV], fh_sh[kLV];
  __shared__ float smx[8];

  unsigned seq = 0;
  auto gridbar = [&]() {                      // proven r2/r5/r6 shape
    ++seq;
    __syncthreads();
    if (tid == 0) __builtin_amdgcn_fence(__ATOMIC_RELEASE, "agent");
    if (bid == 0) {
      if (tid >= 1 && tid < kNBLK) {
        while (ld_flag(&flags[tid * 16]) != seq) __builtin_amdgcn_s_sleep(2);
      }
      __syncthreads();
      if (tid == 0) st_flag(genp, seq);
    } else {
      if (tid == 0) {
        st_flag(&flags[bid * 16], seq);
        while (ld_flag(genp) != seq) __builtin_amdgcn_s_sleep(2);
      }
      __syncthreads();
    }
    asm volatile("" ::: "memory");
  };

  // ---- roles ----
  const int role = bid >> 7;                  // 0: layer0, 1: layer1
  const int g    = bid & 127;
  const int K    = role ? 2048 : 1536;
  const int ngr  = K >> 3;                    // 16B granules per col (256/192)
  const float* bl = role ? bl1 : bl0;
  const float* bv = role ? bv1 : bv0;
  float* gates = role ? gates1 : gates0;
  float* hbuf  = role ? h1 : h0;
  const ushort_t* wf = role ? wf1u : wf0u;

  const int s_  = tid & 15;                   // K-slice within 512-seg (32 floats)
  const int row = tid >> 4;                   // batch row 0..31
  const int pb  = g >> 2;                     // phase-B row
  const int qq4 = g & 3;                      // phase-B col quarter

  // ---- one-time: weights global(fp16) -> LDS, granule-permuted ----
  {
    for (int cc = 0; cc < kCPB; ++cc) {
      int jcol = (cc < 32) ? (g * 32 + cc) : (4096 + g * 2 + (cc - 32));
      const uint4* src = (const uint4*)(wf + (size_t)jcol * K);
      for (int kg = tid; kg < ngr; kg += kNTHR) {
        int si = kg >> 6, kgs = kg & 63;
        int s2 = kgs >> 2, j2 = kgs & 3;
        wlds4[cc * ngr + (si << 6) + (j2 << 4) + s2] = src[kg];
      }
    }
    __syncthreads();
  }

  // zero h0,h1
  {
    int idx = bid * kNTHR + tid;
    if (idx < 2 * kB * kH) h0[idx] = 0.f;
  }
  float creg = 0.f;
  gridbar();

  float acc[kCPB];
  uint4 cmb[4];

  // FMA one 512-k segment: cmb = this thread's packed comb slice (32 halfs)
  auto do_seg = [&](int si) {
    const uint4* wp0 = &wlds4[(si << 6) + s_];
#pragma unroll
    for (int cc = 0; cc < kCPB; ++cc) {
      const uint4* wp = wp0 + cc * ngr;
      uint4 w0 = wp[0], w1 = wp[16], w2 = wp[32], w3 = wp[48];
      float a = acc[cc];
      a = fdot2(cmb[0].x, w0.x, a); a = fdot2(cmb[0].y, w0.y, a);
      a = fdot2(cmb[0].z, w0.z, a); a = fdot2(cmb[0].w, w0.w, a);
      a = fdot2(cmb[1].x, w1.x, a); a = fdot2(cmb[1].y, w1.y, a);
      a = fdot2(cmb[1].z, w1.z, a); a = fdot2(cmb[1].w, w1.w, a);
      a = fdot2(cmb[2].x, w2.x, a); a = fdot2(cmb[2].y, w2.y, a);
      a = fdot2(cmb[2].z, w2.z, a); a = fdot2(cmb[2].w, w2.w, a);
      a = fdot2(cmb[3].x, w3.x, a); a = fdot2(cmb[3].y, w3.y, a);
      a = fdot2(cmb[3].z, w3.z, a); a = fdot2(cmb[3].w, w3.w, a);
      acc[cc] = a;
    }
  };
  auto pack = [&](const vfloat4 v[8]) {
#pragma unroll
    for (int j = 0; j < 4; ++j) {
      cmb[j].x = pkrtz(v[2 * j].x, v[2 * j].y);
      cmb[j].y = pkrtz(v[2 * j].z, v[2 * j].w);
      cmb[j].z = pkrtz(v[2 * j + 1].x, v[2 * j + 1].y);
      cmb[j].w = pkrtz(v[2 * j + 1].z, v[2 * j + 1].w);
    }
  };

  for (int e = 0; e <= kT; ++e) {
    const bool act = (role == 0) ? (e < kT) : (e >= 1);
    const int t = (role == 0) ? e : e - 1;

    // ========== Phase A: gates = [x_t, h] @ W^T + b ==========
    if (act) {
#pragma unroll
      for (int cc = 0; cc < kCPB; ++cc) acc[cc] = 0.f;
      vfloat4 v[8];
      if (role == 0) {
        // seg 0: x (immutable -> plain cached loads)
        const float* px = x + ((size_t)row * kT + t) * kD + s_ * 32;
#pragma unroll
        for (int i = 0; i < 8; ++i) v[i] = *(const vfloat4*)(px + i * 4);
        pack(v); do_seg(0);
        // segs 1,2: h0 (mutable -> coherent batch)
        for (int si = 1; si < 3; ++si) {
          ld_sc_x8(v, hbuf + (size_t)row * kH + (si - 1) * 512 + s_ * 32);
          pack(v); do_seg(si);
        }
      } else {
        // segs 0,1: out[:, t] (mutable -> coherent batch)
        for (int si = 0; si < 2; ++si) {
          ld_sc_x8(v, out + ((size_t)row * kT + t) * kH + si * 512 + s_ * 32);
          pack(v); do_seg(si);
        }
        // segs 2,3: h1
        for (int si = 2; si < 4; ++si) {
          ld_sc_x8(v, hbuf + (size_t)row * kH + (si - 2) * 512 + s_ * 32);
          pack(v); do_seg(si);
        }
      }
      // in-wave reduce over the 16 K-slices (s = lane bits 0..3)
#pragma unroll
      for (int cc = 0; cc < kCPB; ++cc) {
        float a = acc[cc];
        a += __shfl_xor(a, 1);
        a += __shfl_xor(a, 2);
        a += __shfl_xor(a, 4);
        a += __shfl_xor(a, 8);
        acc[cc] = a;
      }
      if (s_ == 0) {
#pragma unroll
        for (int cc = 0; cc < kCPB; ++cc) {
          int j = (cc < 32) ? (g * 32 + cc) : (4096 + g * 2 + (cc - 32));
          float bias = (cc < 32) ? bl[g * 32 + cc] : bv[g * 2 + (cc - 32)];
          gates[(size_t)row * kNG + j] = acc[cc] + bias;  // plain; fence flushes
        }
      }
    }
    gridbar();

    // ========== Phase B: master gates + cell update ==========
    if (act) {
      const float* gr = gates + (size_t)pb * kNG;
      const int lane = tid & 63, wv2 = tid >> 6;
      const bool sm = tid < 128;
      const bool cl = tid < 256;

      float vi = 0.f, vf = 0.f, vo = 0.f, vg = 0.f;
      int j = qq4 * 256 + tid;
      if (cl) {                               // hoisted: latency under softmax
        vi = ld_coh(gr + j);
        vf = ld_coh(gr + kH + j);
        vo = ld_coh(gr + 2 * kH + j);
        vg = ld_coh(gr + 3 * kH + j);
      }

      float ai = 0.f, af = 0.f;
      if (sm) { ai = ld_coh(gr + 4096 + tid); af = ld_coh(gr + 4096 + kLV + tid); }
      float mi = ai, mf = af;
      if (sm) {
#pragma unroll
        for (int d2 = 32; d2 > 0; d2 >>= 1) {
          mi = fmaxf(mi, __shfl_xor(mi, d2));
          mf = fmaxf(mf, __shfl_xor(mf, d2));
        }
        if (lane == 0) { smx[wv2] = mi; smx[2 + wv2] = mf; }
      }
      __syncthreads();
      mi = fmaxf(smx[0], smx[1]);
      mf = fmaxf(smx[2], smx[3]);
      float ei = 0.f, Pi = 0.f, Pf = 0.f;
      if (sm) {
        ei = __expf(ai - mi);
        float ef = __expf(af - mf);
        Pi = ei; Pf = ef;
#pragma unroll
        for (int d2 = 1; d2 < 64; d2 <<= 1) {
          float ni = __shfl_up(Pi, d2);
          float nf = __shfl_up(Pf, d2);
          if (lane >= d2) { Pi += ni; Pf += nf; }
        }
        if (lane == 63) { smx[4 + wv2] = Pi; smx[6 + wv2] = Pf; }
      }
      __syncthreads();
      float Si = smx[4] + smx[5], Sf = smx[6] + smx[7];
      if (sm) {
        if (wv2 == 1) { Pi += smx[4]; Pf += smx[6]; }
        ih_sh[tid] = Pf / Sf;                 // cumsum(softmax(cc_f_h))
        fh_sh[tid] = (Si - Pi + ei) / Si;     // rev-cumsum(softmax(rev cc_i_h))
      }
      __syncthreads();
      if (cl) {
        float i_ = 1.f / (1.f + __expf(-vi));
        float f_ = 1.f / (1.f + __expf(-vf));
        float o_ = 1.f / (1.f + __expf(-vo));
        float g_ = tanhf(vg);
        int l2 = j >> 3;
        float ih = ih_sh[l2], fh = fh_sh[l2];
        float w  = ih * fh;
        float cold = creg;
        float cn = w * (f_ * cold + i_ * g_) + (fh - w) * cold + (ih - w) * g_;
        float hn = o_ * tanhf(cn);
        creg = cn;
        hbuf[(size_t)pb * kH + j] = hn;                  // plain; fence flushes
        out[((size_t)pb * kT + t) * kH + j] = hn;        // plain; fence flushes
      }
    }
    gridbar();
  }
}

extern "C" void kernel_launch(void* const* d_in, const int* in_sizes, int n_in,
                              void* d_out, int out_size, void* d_ws, size_t ws_size,
                              hipStream_t stream) {
  const float* x   = (const float*)d_in[0];
  const float* Wl0 = (const float*)d_in[1];
  const float* bl0 = (const float*)d_in[2];
  const float* Wv0 = (const float*)d_in[3];
  const float* bv0 = (const float*)d_in[4];
  const float* Wl1 = (const float*)d_in[5];
  const float* bl1 = (const float*)d_in[6];
  const float* Wv1 = (const float*)d_in[7];
  const float* bv1 = (const float*)d_in[8];
  (void)in_sizes; (void)n_in; (void)out_size; (void)ws_size;

  float* ws = (float*)d_ws;
  ushort_t* wf0 = (ushort_t*)(ws + kOffWF);                 // [4352][1536] fp16
  ushort_t* wf1 = wf0 + (size_t)4352 * 1536;                // [4352][2048] fp16

  // pre-pass: convert weights to fp16 (Wl then Wv rows, per layer)
  {
    int n;
    n = 4096 * 1536 / 8;
    cvt_fp16_kernel<<<(n + 255) / 256, 256, 0, stream>>>(Wl0, wf0, n);
    n = 256 * 1536 / 8;
    cvt_fp16_kernel<<<(n + 255) / 256, 256, 0, stream>>>(
        Wv0, wf0 + (size_t)4096 * 1536, n);
    n = 4096 * 2048 / 8;
    cvt_fp16_kernel<<<(n + 255) / 256, 256, 0, stream>>>(Wl1, wf1, n);
    n = 256 * 2048 / 8;
    cvt_fp16_kernel<<<(n + 255) / 256, 256, 0, stream>>>(
        Wv1, wf1 + (size_t)4096 * 2048, n);
  }

  onlstm_kernel<<<dim3(kNBLK), dim3(kNTHR), 0, stream>>>(
      x, bl0, bv0, bl1, bv1, wf0, wf1, (float*)d_out, ws);
}

// Round 8
// 29460.703 us; speedup vs baseline: 4.5752x; 1.4028x over previous
//
#include <hip/hip_runtime.h>

namespace {
constexpr int kB  = 32;
constexpr int kT  = 1024;
constexpr int kD  = 512;
constexpr int kH  = 1024;
constexpr int kLV = 128;
constexpr int kNG = 4 * kH + 2 * kLV;   // 4352
constexpr int kNBLK = 256;
constexpr int kNTHR = 512;
constexpr int kCPB  = 34;               // 32 lstm + 2 lvl cols per A-block
// ws float offsets
constexpr int kOffH0 = 8192;
constexpr int kOffWF = kOffH0 + 2 * kB * kH + 2 * kB * kNG;
}

typedef float vfloat4 __attribute__((ext_vector_type(4)));
typedef _Float16 half2_t __attribute__((ext_vector_type(2)));
typedef _Float16 half8_t __attribute__((ext_vector_type(8)));
typedef unsigned short ushort_t;

static __device__ __forceinline__ unsigned ld_flag(const unsigned* p) {
  return __hip_atomic_load(p, __ATOMIC_RELAXED, __HIP_MEMORY_SCOPE_AGENT);
}
static __device__ __forceinline__ void st_flag(unsigned* p, unsigned v) {
  __hip_atomic_store(p, v, __ATOMIC_RELAXED, __HIP_MEMORY_SCOPE_AGENT);
}
static __device__ __forceinline__ float ld_coh(const float* p) {
  return __hip_atomic_load(p, __ATOMIC_RELAXED, __HIP_MEMORY_SCOPE_AGENT);
}
// write-through store to the coherent point (no dirty-L2 state)
static __device__ __forceinline__ void st_wt(float* p, float v) {
  asm volatile("global_store_dword %0, %1, off sc0 sc1" :: "v"(p), "v"(v) : "memory");
}
// 8 coherent 16B loads, overlapped, completed INSIDE one asm block (proven r5-r7).
static __device__ __forceinline__ void ld_sc_x8(vfloat4 v[8], const float* b) {
  asm volatile(
      "global_load_dwordx4 %0, %8, off sc0 sc1\n\t"
      "global_load_dwordx4 %1, %9, off sc0 sc1\n\t"
      "global_load_dwordx4 %2, %10, off sc0 sc1\n\t"
      "global_load_dwordx4 %3, %11, off sc0 sc1\n\t"
      "global_load_dwordx4 %4, %12, off sc0 sc1\n\t"
      "global_load_dwordx4 %5, %13, off sc0 sc1\n\t"
      "global_load_dwordx4 %6, %14, off sc0 sc1\n\t"
      "global_load_dwordx4 %7, %15, off sc0 sc1\n\t"
      "s_waitcnt vmcnt(0)"
      : "=&v"(v[0]), "=&v"(v[1]), "=&v"(v[2]), "=&v"(v[3]),
        "=&v"(v[4]), "=&v"(v[5]), "=&v"(v[6]), "=&v"(v[7])
      : "v"(b), "v"(b + 4), "v"(b + 8), "v"(b + 12),
        "v"(b + 16), "v"(b + 20), "v"(b + 24), "v"(b + 28)
      : "memory");
}
static __device__ __forceinline__ float fdot2(unsigned a, unsigned b, float c) {
  return __builtin_amdgcn_fdot2(__builtin_bit_cast(half2_t, a),
                                __builtin_bit_cast(half2_t, b), c, false);
}
static __device__ __forceinline__ unsigned pkrtz(float a, float b) {
  return __builtin_bit_cast(unsigned, __builtin_amdgcn_cvt_pkrtz(a, b));
}

// -------- fp32 -> fp16 weight conversion (one-time pre-pass) --------
__global__ __launch_bounds__(256) void cvt_fp16_kernel(
    const float* __restrict__ src, ushort_t* __restrict__ dst, int n8) {
  int i = blockIdx.x * 256 + threadIdx.x;
  if (i >= n8) return;
  const vfloat4* s4 = (const vfloat4*)src;
  vfloat4 a = s4[2 * i], b = s4[2 * i + 1];
  half8_t o;
  o[0] = (_Float16)a.x; o[1] = (_Float16)a.y;
  o[2] = (_Float16)a.z; o[3] = (_Float16)a.w;
  o[4] = (_Float16)b.x; o[5] = (_Float16)b.y;
  o[6] = (_Float16)b.z; o[7] = (_Float16)b.w;
  ((half8_t*)dst)[i] = o;
}

__global__ __launch_bounds__(kNTHR, 2) void onlstm_kernel(
    const float* __restrict__ x,
    const float* __restrict__ bl0, const float* __restrict__ bv0,
    const float* __restrict__ bl1, const float* __restrict__ bv1,
    const ushort_t* __restrict__ wf0u, const ushort_t* __restrict__ wf1u,
    float* __restrict__ out, float* __restrict__ ws)
{
  const int tid = threadIdx.x;
  const int bid = blockIdx.x;

  // ---- workspace ----
  unsigned* flags = (unsigned*)ws;            // [256] stride-16 uints
  unsigned* genp  = (unsigned*)ws + 4096;
  float* h0     = ws + kOffH0;                // [32][1024]
  float* h1     = h0 + kB * kH;
  float* gates0 = h1 + kB * kH;               // [32][4352]
  float* gates1 = gates0 + kB * kNG;

  // LDS: weights as 16B granules, permuted (p = j*16 + s within each 512-k seg)
  __shared__ uint4 wlds4[kCPB * 256];         // 139,264 B
  __shared__ float ih_sh[kLV], fh_sh[kLV];
  __shared__ float smx[8];

  unsigned seq = 0;
  // flags-only barrier: every thread drains its own write-through stores
  // (vmcnt(0)) BEFORE syncthreads, so data is at the coherent point when
  // the flag is published. No L2-writeback fence.
  auto gridbar = [&]() {
    ++seq;
    asm volatile("s_waitcnt vmcnt(0)" ::: "memory");
    __syncthreads();
    if (bid == 0) {
      if (tid >= 1 && tid < kNBLK) {
        while (ld_flag(&flags[tid * 16]) != seq) __builtin_amdgcn_s_sleep(2);
      }
      __syncthreads();
      if (tid == 0) st_flag(genp, seq);
    } else {
      if (tid == 0) {
        st_flag(&flags[bid * 16], seq);
        while (ld_flag(genp) != seq) __builtin_amdgcn_s_sleep(2);
      }
      __syncthreads();
    }
    asm volatile("" ::: "memory");
  };

  // ---- roles ----
  const int role = bid >> 7;                  // 0: layer0, 1: layer1
  const int g    = bid & 127;
  const int K    = role ? 2048 : 1536;
  const int ngr  = K >> 3;                    // 16B granules per col (256/192)
  const float* bl = role ? bl1 : bl0;
  const float* bv = role ? bv1 : bv0;
  float* gates = role ? gates1 : gates0;
  float* hbuf  = role ? h1 : h0;
  const ushort_t* wf = role ? wf1u : wf0u;

  const int s_  = tid & 15;                   // K-slice within 512-seg (32 floats)
  const int row = tid >> 4;                   // batch row 0..31
  const int pb  = g >> 2;                     // phase-B row
  const int qq4 = g & 3;                      // phase-B col quarter

  // ---- one-time: weights global(fp16) -> LDS, granule-permuted ----
  {
    for (int cc = 0; cc < kCPB; ++cc) {
      int jcol = (cc < 32) ? (g * 32 + cc) : (4096 + g * 2 + (cc - 32));
      const uint4* src = (const uint4*)(wf + (size_t)jcol * K);
      for (int kg = tid; kg < ngr; kg += kNTHR) {
        int si = kg >> 6, kgs = kg & 63;
        int s2 = kgs >> 2, j2 = kgs & 3;
        wlds4[cc * ngr + (si << 6) + (j2 << 4) + s2] = src[kg];
      }
    }
    __syncthreads();
  }

  // zero h0,h1 (write-through)
  {
    int idx = bid * kNTHR + tid;
    if (idx < 2 * kB * kH) st_wt(h0 + idx, 0.f);
  }
  float creg = 0.f;
  gridbar();

  float acc[kCPB];
  uint4 cmb[4];

  // FMA one 512-k segment: cmb = this thread's packed comb slice (32 halfs)
  auto do_seg = [&](int si) {
    const uint4* wp0 = &wlds4[(si << 6) + s_];
#pragma unroll
    for (int cc = 0; cc < kCPB; ++cc) {
      const uint4* wp = wp0 + cc * ngr;
      uint4 w0 = wp[0], w1 = wp[16], w2 = wp[32], w3 = wp[48];
      float a = acc[cc];
      a = fdot2(cmb[0].x, w0.x, a); a = fdot2(cmb[0].y, w0.y, a);
      a = fdot2(cmb[0].z, w0.z, a); a = fdot2(cmb[0].w, w0.w, a);
      a = fdot2(cmb[1].x, w1.x, a); a = fdot2(cmb[1].y, w1.y, a);
      a = fdot2(cmb[1].z, w1.z, a); a = fdot2(cmb[1].w, w1.w, a);
      a = fdot2(cmb[2].x, w2.x, a); a = fdot2(cmb[2].y, w2.y, a);
      a = fdot2(cmb[2].z, w2.z, a); a = fdot2(cmb[2].w, w2.w, a);
      a = fdot2(cmb[3].x, w3.x, a); a = fdot2(cmb[3].y, w3.y, a);
      a = fdot2(cmb[3].z, w3.z, a); a = fdot2(cmb[3].w, w3.w, a);
      acc[cc] = a;
    }
  };
  auto pack = [&](const vfloat4 v[8]) {
#pragma unroll
    for (int j = 0; j < 4; ++j) {
      cmb[j].x = pkrtz(v[2 * j].x, v[2 * j].y);
      cmb[j].y = pkrtz(v[2 * j].z, v[2 * j].w);
      cmb[j].z = pkrtz(v[2 * j + 1].x, v[2 * j + 1].y);
      cmb[j].w = pkrtz(v[2 * j + 1].z, v[2 * j + 1].w);
    }
  };

  for (int e = 0; e <= kT; ++e) {
    const bool act = (role == 0) ? (e < kT) : (e >= 1);
    const int t = (role == 0) ? e : e - 1;

    // ========== Phase A: gates = [x_t, h] @ W^T + b ==========
    if (act) {
#pragma unroll
      for (int cc = 0; cc < kCPB; ++cc) acc[cc] = 0.f;
      vfloat4 v[8];
      if (role == 0) {
        // seg 0: x (immutable -> plain cached loads)
        const float* px = x + ((size_t)row * kT + t) * kD + s_ * 32;
#pragma unroll
        for (int i = 0; i < 8; ++i) v[i] = *(const vfloat4*)(px + i * 4);
        pack(v); do_seg(0);
        // segs 1,2: h0 (mutable -> coherent batch)
        for (int si = 1; si < 3; ++si) {
          ld_sc_x8(v, hbuf + (size_t)row * kH + (si - 1) * 512 + s_ * 32);
          pack(v); do_seg(si);
        }
      } else {
        // segs 0,1: out[:, t] (mutable -> coherent batch)
        for (int si = 0; si < 2; ++si) {
          ld_sc_x8(v, out + ((size_t)row * kT + t) * kH + si * 512 + s_ * 32);
          pack(v); do_seg(si);
        }
        // segs 2,3: h1
        for (int si = 2; si < 4; ++si) {
          ld_sc_x8(v, hbuf + (size_t)row * kH + (si - 2) * 512 + s_ * 32);
          pack(v); do_seg(si);
        }
      }
      // in-wave reduce over the 16 K-slices (s = lane bits 0..3)
#pragma unroll
      for (int cc = 0; cc < kCPB; ++cc) {
        float a = acc[cc];
        a += __shfl_xor(a, 1);
        a += __shfl_xor(a, 2);
        a += __shfl_xor(a, 4);
        a += __shfl_xor(a, 8);
        acc[cc] = a;
      }
      if (s_ == 0) {
#pragma unroll
        for (int cc = 0; cc < kCPB; ++cc) {
          int j = (cc < 32) ? (g * 32 + cc) : (4096 + g * 2 + (cc - 32));
          float bias = (cc < 32) ? bl[g * 32 + cc] : bv[g * 2 + (cc - 32)];
          st_wt(gates + (size_t)row * kNG + j, acc[cc] + bias);
        }
      }
    }
    gridbar();

    // ========== Phase B: master gates + cell update ==========
    if (act) {
      const float* gr = gates + (size_t)pb * kNG;
      const int lane = tid & 63, wv2 = tid >> 6;
      const bool sm = tid < 128;
      const bool cl = tid < 256;

      float vi = 0.f, vf = 0.f, vo = 0.f, vg = 0.f;
      int j = qq4 * 256 + tid;
      if (cl) {                               // hoisted: latency under softmax
        vi = ld_coh(gr + j);
        vf = ld_coh(gr + kH + j);
        vo = ld_coh(gr + 2 * kH + j);
        vg = ld_coh(gr + 3 * kH + j);
      }

      float ai = 0.f, af = 0.f;
      if (sm) { ai = ld_coh(gr + 4096 + tid); af = ld_coh(gr + 4096 + kLV + tid); }
      float mi = ai, mf = af;
      if (sm) {
#pragma unroll
        for (int d2 = 32; d2 > 0; d2 >>= 1) {
          mi = fmaxf(mi, __shfl_xor(mi, d2));
          mf = fmaxf(mf, __shfl_xor(mf, d2));
        }
        if (lane == 0) { smx[wv2] = mi; smx[2 + wv2] = mf; }
      }
      __syncthreads();
      mi = fmaxf(smx[0], smx[1]);
      mf = fmaxf(smx[2], smx[3]);
      float ei = 0.f, Pi = 0.f, Pf = 0.f;
      if (sm) {
        ei = __expf(ai - mi);
        float ef = __expf(af - mf);
        Pi = ei; Pf = ef;
#pragma unroll
        for (int d2 = 1; d2 < 64; d2 <<= 1) {
          float ni = __shfl_up(Pi, d2);
          float nf = __shfl_up(Pf, d2);
          if (lane >= d2) { Pi += ni; Pf += nf; }
        }
        if (lane == 63) { smx[4 + wv2] = Pi; smx[6 + wv2] = Pf; }
      }
      __syncthreads();
      float Si = smx[4] + smx[5], Sf = smx[6] + smx[7];
      if (sm) {
        if (wv2 == 1) { Pi += smx[4]; Pf += smx[6]; }
        ih_sh[tid] = Pf / Sf;                 // cumsum(softmax(cc_f_h))
        fh_sh[tid] = (Si - Pi + ei) / Si;     // rev-cumsum(softmax(rev cc_i_h))
      }
      __syncthreads();
      if (cl) {
        float i_ = 1.f / (1.f + __expf(-vi));
        float f_ = 1.f / (1.f + __expf(-vf));
        float o_ = 1.f / (1.f + __expf(-vo));
        float g_ = tanhf(vg);
        int l2 = j >> 3;
        float ih = ih_sh[l2], fh = fh_sh[l2];
        float w  = ih * fh;
        float cold = creg;
        float cn = w * (f_ * cold + i_ * g_) + (fh - w) * cold + (ih - w) * g_;
        float hn = o_ * tanhf(cn);
        creg = cn;
        st_wt(hbuf + (size_t)pb * kH + j, hn);
        st_wt(out + ((size_t)pb * kT + t) * kH + j, hn);
      }
    }
    gridbar();
  }
}

extern "C" void kernel_launch(void* const* d_in, const int* in_sizes, int n_in,
                              void* d_out, int out_size, void* d_ws, size_t ws_size,
                              hipStream_t stream) {
  const float* x   = (const float*)d_in[0];
  const float* Wl0 = (const float*)d_in[1];
  const float* bl0 = (const float*)d_in[2];
  const float* Wv0 = (const float*)d_in[3];
  const float* bv0 = (const float*)d_in[4];
  const float* Wl1 = (const float*)d_in[5];
  const float* bl1 = (const float*)d_in[6];
  const float* Wv1 = (const float*)d_in[7];
  const float* bv1 = (const float*)d_in[8];
  (void)in_sizes; (void)n_in; (void)out_size; (void)ws_size;

  float* ws = (float*)d_ws;
  ushort_t* wf0 = (ushort_t*)(ws + kOffWF);                 // [4352][1536] fp16
  ushort_t* wf1 = wf0 + (size_t)4352 * 1536;                // [4352][2048] fp16

  // pre-pass: convert weights to fp16 (Wl then Wv rows, per layer)
  {
    int n;
    n = 4096 * 1536 / 8;
    cvt_fp16_kernel<<<(n + 255) / 256, 256, 0, stream>>>(Wl0, wf0, n);
    n = 256 * 1536 / 8;
    cvt_fp16_kernel<<<(n + 255) / 256, 256, 0, stream>>>(
        Wv0, wf0 + (size_t)4096 * 1536, n);
    n = 4096 * 2048 / 8;
    cvt_fp16_kernel<<<(n + 255) / 256, 256, 0, stream>>>(Wl1, wf1, n);
    n = 256 * 2048 / 8;
    cvt_fp16_kernel<<<(n + 255) / 256, 256, 0, stream>>>(
        Wv1, wf1 + (size_t)4096 * 2048, n);
  }

  onlstm_kernel<<<dim3(kNBLK), dim3(kNTHR), 0, stream>>>(
      x, bl0, bv0, bl1, bv1, wf0, wf1, (float*)d_out, ws);
}

// Round 9
// 29037.485 us; speedup vs baseline: 4.6419x; 1.0146x over previous
//
#include <hip/hip_runtime.h>

namespace {
constexpr int kB  = 32;
constexpr int kT  = 1024;
constexpr int kD  = 512;
constexpr int kH  = 1024;
constexpr int kLV = 128;
constexpr int kNG = 4 * kH + 2 * kLV;   // 4352
constexpr int kNBLK = 256;
constexpr int kNTHR = 512;
constexpr int kCPB  = 34;               // 32 lstm + 2 lvl cols per A-block
// ws float offsets
constexpr int kOffH0 = 8192;
constexpr int kOffWF = kOffH0 + 2 * kB * kH + 2 * kB * kNG;
}

typedef float vfloat4 __attribute__((ext_vector_type(4)));
typedef _Float16 half2_t __attribute__((ext_vector_type(2)));
typedef _Float16 half8_t __attribute__((ext_vector_type(8)));
typedef unsigned short ushort_t;

static __device__ __forceinline__ unsigned ld_flag(const unsigned* p) {
  return __hip_atomic_load(p, __ATOMIC_RELAXED, __HIP_MEMORY_SCOPE_AGENT);
}
static __device__ __forceinline__ void st_flag(unsigned* p, unsigned v) {
  __hip_atomic_store(p, v, __ATOMIC_RELAXED, __HIP_MEMORY_SCOPE_AGENT);
}
static __device__ __forceinline__ float ld_coh(const float* p) {
  return __hip_atomic_load(p, __ATOMIC_RELAXED, __HIP_MEMORY_SCOPE_AGENT);
}
// write-through store to the coherent point (no dirty-L2 state)
static __device__ __forceinline__ void st_wt(float* p, float v) {
  asm volatile("global_store_dword %0, %1, off sc0 sc1" :: "v"(p), "v"(v) : "memory");
}
// 8 coherent 16B loads, overlapped, completed INSIDE one asm block (proven r5-r8).
static __device__ __forceinline__ void ld_sc_x8(vfloat4 v[8], const float* b) {
  asm volatile(
      "global_load_dwordx4 %0, %8, off sc0 sc1\n\t"
      "global_load_dwordx4 %1, %9, off sc0 sc1\n\t"
      "global_load_dwordx4 %2, %10, off sc0 sc1\n\t"
      "global_load_dwordx4 %3, %11, off sc0 sc1\n\t"
      "global_load_dwordx4 %4, %12, off sc0 sc1\n\t"
      "global_load_dwordx4 %5, %13, off sc0 sc1\n\t"
      "global_load_dwordx4 %6, %14, off sc0 sc1\n\t"
      "global_load_dwordx4 %7, %15, off sc0 sc1\n\t"
      "s_waitcnt vmcnt(0)"
      : "=&v"(v[0]), "=&v"(v[1]), "=&v"(v[2]), "=&v"(v[3]),
        "=&v"(v[4]), "=&v"(v[5]), "=&v"(v[6]), "=&v"(v[7])
      : "v"(b), "v"(b + 4), "v"(b + 8), "v"(b + 12),
        "v"(b + 16), "v"(b + 20), "v"(b + 24), "v"(b + 28)
      : "memory");
}
static __device__ __forceinline__ float fdot2(unsigned a, unsigned b, float c) {
  return __builtin_amdgcn_fdot2(__builtin_bit_cast(half2_t, a),
                                __builtin_bit_cast(half2_t, b), c, false);
}
static __device__ __forceinline__ unsigned pkrtz(float a, float b) {
  return __builtin_bit_cast(unsigned, __builtin_amdgcn_cvt_pkrtz(a, b));
}

// -------- fp32 -> fp16 weight conversion (one-time pre-pass) --------
__global__ __launch_bounds__(256) void cvt_fp16_kernel(
    const float* __restrict__ src, ushort_t* __restrict__ dst, int n8) {
  int i = blockIdx.x * 256 + threadIdx.x;
  if (i >= n8) return;
  const vfloat4* s4 = (const vfloat4*)src;
  vfloat4 a = s4[2 * i], b = s4[2 * i + 1];
  half8_t o;
  o[0] = (_Float16)a.x; o[1] = (_Float16)a.y;
  o[2] = (_Float16)a.z; o[3] = (_Float16)a.w;
  o[4] = (_Float16)b.x; o[5] = (_Float16)b.y;
  o[6] = (_Float16)b.z; o[7] = (_Float16)b.w;
  ((half8_t*)dst)[i] = o;
}

__global__ __launch_bounds__(kNTHR, 2) void onlstm_kernel(
    const float* __restrict__ x,
    const float* __restrict__ bl0, const float* __restrict__ bv0,
    const float* __restrict__ bl1, const float* __restrict__ bv1,
    const ushort_t* __restrict__ wf0u, const ushort_t* __restrict__ wf1u,
    float* __restrict__ out, float* __restrict__ ws)
{
  const int tid = threadIdx.x;
  const int bid = blockIdx.x;

  // ---- workspace ----
  unsigned* flags = (unsigned*)ws;            // [256] stride-16 uints
  unsigned* genp  = (unsigned*)ws + 4096;
  float* h0     = ws + kOffH0;                // [32][1024]
  float* h1     = h0 + kB * kH;
  float* gates0 = h1 + kB * kH;               // [32][4352]
  float* gates1 = gates0 + kB * kNG;

  // LDS: weights as 16B granules, permuted (p = j*16 + s within each 512-k seg)
  __shared__ uint4 wlds4[kCPB * 256];         // 139,264 B
  __shared__ float gst[kB][37];               // 4,736 B gate-store bounce (pad 37)
  __shared__ float ih_sh[kLV], fh_sh[kLV];
  __shared__ float smx[8];

  unsigned seq = 0;
  // flags-only barrier (proven r8): every thread drains its own write-through
  // stores (vmcnt(0)) BEFORE syncthreads, so data is at the coherent point
  // when the flag is published. No L2-writeback fence.
  auto gridbar = [&]() {
    ++seq;
    asm volatile("s_waitcnt vmcnt(0)" ::: "memory");
    __syncthreads();
    if (bid == 0) {
      if (tid >= 1 && tid < kNBLK) {
        while (ld_flag(&flags[tid * 16]) != seq) __builtin_amdgcn_s_sleep(2);
      }
      __syncthreads();
      if (tid == 0) st_flag(genp, seq);
    } else {
      if (tid == 0) {
        st_flag(&flags[bid * 16], seq);
        while (ld_flag(genp) != seq) __builtin_amdgcn_s_sleep(2);
      }
      __syncthreads();
    }
    asm volatile("" ::: "memory");
  };

  // ---- roles ----
  const int role = bid >> 7;                  // 0: layer0, 1: layer1
  const int g    = bid & 127;
  const int K    = role ? 2048 : 1536;
  const int ngr  = K >> 3;                    // 16B granules per col (256/192)
  const float* bl = role ? bl1 : bl0;
  const float* bv = role ? bv1 : bv0;
  float* gates = role ? gates1 : gates0;
  float* hbuf  = role ? h1 : h0;
  const ushort_t* wf = role ? wf1u : wf0u;

  const int s_  = tid & 15;                   // K-slice within 512-seg (32 floats)
  const int row = tid >> 4;                   // batch row 0..31
  const int pb  = g >> 2;                     // phase-B row
  const int qq4 = g & 3;                      // phase-B col quarter

  // ---- one-time: weights global(fp16) -> LDS, granule-permuted ----
  {
    for (int cc = 0; cc < kCPB; ++cc) {
      int jcol = (cc < 32) ? (g * 32 + cc) : (4096 + g * 2 + (cc - 32));
      const uint4* src = (const uint4*)(wf + (size_t)jcol * K);
      for (int kg = tid; kg < ngr; kg += kNTHR) {
        int si = kg >> 6, kgs = kg & 63;
        int s2 = kgs >> 2, j2 = kgs & 3;
        wlds4[cc * ngr + (si << 6) + (j2 << 4) + s2] = src[kg];
      }
    }
    __syncthreads();
  }

  // zero h0,h1 (write-through)
  {
    int idx = bid * kNTHR + tid;
    if (idx < 2 * kB * kH) st_wt(h0 + idx, 0.f);
  }
  float creg = 0.f;
  gridbar();

  float acc[kCPB];
  uint4 cmb[4];

  // FMA one 512-k segment: cmb = this thread's packed comb slice (32 halfs)
  auto do_seg = [&](int si) {
    const uint4* wp0 = &wlds4[(si << 6) + s_];
#pragma unroll
    for (int cc = 0; cc < kCPB; ++cc) {
      const uint4* wp = wp0 + cc * ngr;
      uint4 w0 = wp[0], w1 = wp[16], w2 = wp[32], w3 = wp[48];
      float a = acc[cc];
      a = fdot2(cmb[0].x, w0.x, a); a = fdot2(cmb[0].y, w0.y, a);
      a = fdot2(cmb[0].z, w0.z, a); a = fdot2(cmb[0].w, w0.w, a);
      a = fdot2(cmb[1].x, w1.x, a); a = fdot2(cmb[1].y, w1.y, a);
      a = fdot2(cmb[1].z, w1.z, a); a = fdot2(cmb[1].w, w1.w, a);
      a = fdot2(cmb[2].x, w2.x, a); a = fdot2(cmb[2].y, w2.y, a);
      a = fdot2(cmb[2].z, w2.z, a); a = fdot2(cmb[2].w, w2.w, a);
      a = fdot2(cmb[3].x, w3.x, a); a = fdot2(cmb[3].y, w3.y, a);
      a = fdot2(cmb[3].z, w3.z, a); a = fdot2(cmb[3].w, w3.w, a);
      acc[cc] = a;
    }
  };
  auto pack = [&](const vfloat4 v[8]) {
#pragma unroll
    for (int j = 0; j < 4; ++j) {
      cmb[j].x = pkrtz(v[2 * j].x, v[2 * j].y);
      cmb[j].y = pkrtz(v[2 * j].z, v[2 * j].w);
      cmb[j].z = pkrtz(v[2 * j + 1].x, v[2 * j + 1].y);
      cmb[j].w = pkrtz(v[2 * j + 1].z, v[2 * j + 1].w);
    }
  };

  for (int e = 0; e <= kT; ++e) {
    const bool act = (role == 0) ? (e < kT) : (e >= 1);
    const int t = (role == 0) ? e : e - 1;

    // ========== Phase A: gates = [x_t, h] @ W^T + b ==========
    if (act) {
#pragma unroll
      for (int cc = 0; cc < kCPB; ++cc) acc[cc] = 0.f;
      vfloat4 v[8];
      if (role == 0) {
        // seg 0: x (immutable -> plain cached loads)
        const float* px = x + ((size_t)row * kT + t) * kD + s_ * 32;
#pragma unroll
        for (int i = 0; i < 8; ++i) v[i] = *(const vfloat4*)(px + i * 4);
        pack(v); do_seg(0);
        // segs 1,2: h0 (mutable -> coherent batch)
        for (int si = 1; si < 3; ++si) {
          ld_sc_x8(v, hbuf + (size_t)row * kH + (si - 1) * 512 + s_ * 32);
          pack(v); do_seg(si);
        }
      } else {
        // segs 0,1: out[:, t] (mutable -> coherent batch)
        for (int si = 0; si < 2; ++si) {
          ld_sc_x8(v, out + ((size_t)row * kT + t) * kH + si * 512 + s_ * 32);
          pack(v); do_seg(si);
        }
        // segs 2,3: h1
        for (int si = 2; si < 4; ++si) {
          ld_sc_x8(v, hbuf + (size_t)row * kH + (si - 2) * 512 + s_ * 32);
          pack(v); do_seg(si);
        }
      }
      // in-wave reduce over the 16 K-slices (s = lane bits 0..3)
#pragma unroll
      for (int cc = 0; cc < kCPB; ++cc) {
        float a = acc[cc];
        a += __shfl_xor(a, 1);
        a += __shfl_xor(a, 2);
        a += __shfl_xor(a, 4);
        a += __shfl_xor(a, 8);
        acc[cc] = a;
      }
      // bounce through LDS (pad-37 -> conflict-free), then LANE-COALESCED
      // write-through stores (fix: r8's per-lane scalar stores caused ~16x
      // fabric write amplification, WRITE_SIZE 9.45 GB)
      if (s_ == 0) {
#pragma unroll
        for (int cc = 0; cc < kCPB; ++cc) gst[row][cc] = acc[cc];
      }
      __syncthreads();
      for (int o = tid; o < kB * kCPB; o += kNTHR) {
        int r2 = o / kCPB;
        int cc = o - r2 * kCPB;
        int j = (cc < 32) ? (g * 32 + cc) : (4096 + g * 2 + (cc - 32));
        float bias = (cc < 32) ? bl[g * 32 + cc] : bv[g * 2 + (cc - 32)];
        st_wt(gates + (size_t)r2 * kNG + j, gst[r2][cc] + bias);
      }
    }
    gridbar();

    // ========== Phase B: master gates + cell update ==========
    if (act) {
      const float* gr = gates + (size_t)pb * kNG;
      const int lane = tid & 63, wv2 = tid >> 6;
      const bool sm = tid < 128;
      const bool cl = tid < 256;

      float vi = 0.f, vf = 0.f, vo = 0.f, vg = 0.f;
      int j = qq4 * 256 + tid;
      if (cl) {                               // hoisted: latency under softmax
        vi = ld_coh(gr + j);
        vf = ld_coh(gr + kH + j);
        vo = ld_coh(gr + 2 * kH + j);
        vg = ld_coh(gr + 3 * kH + j);
      }

      float ai = 0.f, af = 0.f;
      if (sm) { ai = ld_coh(gr + 4096 + tid); af = ld_coh(gr + 4096 + kLV + tid); }
      float mi = ai, mf = af;
      if (sm) {
#pragma unroll
        for (int d2 = 32; d2 > 0; d2 >>= 1) {
          mi = fmaxf(mi, __shfl_xor(mi, d2));
          mf = fmaxf(mf, __shfl_xor(mf, d2));
        }
        if (lane == 0) { smx[wv2] = mi; smx[2 + wv2] = mf; }
      }
      __syncthreads();
      mi = fmaxf(smx[0], smx[1]);
      mf = fmaxf(smx[2], smx[3]);
      float ei = 0.f, Pi = 0.f, Pf = 0.f;
      if (sm) {
        ei = __expf(ai - mi);
        float ef = __expf(af - mf);
        Pi = ei; Pf = ef;
#pragma unroll
        for (int d2 = 1; d2 < 64; d2 <<= 1) {
          float ni = __shfl_up(Pi, d2);
          float nf = __shfl_up(Pf, d2);
          if (lane >= d2) { Pi += ni; Pf += nf; }
        }
        if (lane == 63) { smx[4 + wv2] = Pi; smx[6 + wv2] = Pf; }
      }
      __syncthreads();
      float Si = smx[4] + smx[5], Sf = smx[6] + smx[7];
      if (sm) {
        if (wv2 == 1) { Pi += smx[4]; Pf += smx[6]; }
        ih_sh[tid] = Pf / Sf;                 // cumsum(softmax(cc_f_h))
        fh_sh[tid] = (Si - Pi + ei) / Si;     // rev-cumsum(softmax(rev cc_i_h))
      }
      __syncthreads();
      if (cl) {
        float i_ = 1.f / (1.f + __expf(-vi));
        float f_ = 1.f / (1.f + __expf(-vf));
        float o_ = 1.f / (1.f + __expf(-vo));
        float g_ = tanhf(vg);
        int l2 = j >> 3;
        float ih = ih_sh[l2], fh = fh_sh[l2];
        float w  = ih * fh;
        float cold = creg;
        float cn = w * (f_ * cold + i_ * g_) + (fh - w) * cold + (ih - w) * g_;
        float hn = o_ * tanhf(cn);
        creg = cn;
        st_wt(hbuf + (size_t)pb * kH + j, hn);
        st_wt(out + ((size_t)pb * kT + t) * kH + j, hn);
      }
    }
    gridbar();
  }
}

extern "C" void kernel_launch(void* const* d_in, const int* in_sizes, int n_in,
                              void* d_out, int out_size, void* d_ws, size_t ws_size,
                              hipStream_t stream) {
  const float* x   = (const float*)d_in[0];
  const float* Wl0 = (const float*)d_in[1];
  const float* bl0 = (const float*)d_in[2];
  const float* Wv0 = (const float*)d_in[3];
  const float* bv0 = (const float*)d_in[4];
  const float* Wl1 = (const float*)d_in[5];
  const float* bl1 = (const float*)d_in[6];
  const float* Wv1 = (const float*)d_in[7];
  const float* bv1 = (const float*)d_in[8];
  (void)in_sizes; (void)n_in; (void)out_size; (void)ws_size;

  float* ws = (float*)d_ws;
  ushort_t* wf0 = (ushort_t*)(ws + kOffWF);                 // [4352][1536] fp16
  ushort_t* wf1 = wf0 + (size_t)4352 * 1536;                // [4352][2048] fp16

  // pre-pass: convert weights to fp16 (Wl then Wv rows, per layer)
  {
    int n;
    n = 4096 * 1536 / 8;
    cvt_fp16_kernel<<<(n + 255) / 256, 256, 0, stream>>>(Wl0, wf0, n);
    n = 256 * 1536 / 8;
    cvt_fp16_kernel<<<(n + 255) / 256, 256, 0, stream>>>(
        Wv0, wf0 + (size_t)4096 * 1536, n);
    n = 4096 * 2048 / 8;
    cvt_fp16_kernel<<<(n + 255) / 256, 256, 0, stream>>>(Wl1, wf1, n);
    n = 256 * 2048 / 8;
    cvt_fp16_kernel<<<(n + 255) / 256, 256, 0, stream>>>(
        Wv1, wf1 + (size_t)4096 * 2048, n);
  }

  onlstm_kernel<<<dim3(kNBLK), dim3(kNTHR), 0, stream>>>(
      x, bl0, bv0, bl1, bv1, wf0, wf1, (float*)d_out, ws);
}